// Round 14
// baseline (1064.986 us; speedup 1.0000x reference)
//
#include <hip/hip_runtime.h>

typedef unsigned short u16;
typedef unsigned int u32;

#define NNODES 20000
#define NEDGES 640000
// GAMMA = 1/(2*(sqrt(2)/15)^2) = 56.25 exactly
#define RBF_GAMMA 56.25f
#define SQRT2 1.4142135623730951f
#define PITCH 132    // fp32 LDS row pitch
#define BPITCH 136   // bf16 LDS row pitch (u16): 272B rows, 16B-aligned, quad-stride -> free 2-way banks

typedef __bf16 bf16x8 __attribute__((ext_vector_type(8)));
typedef float f32x4 __attribute__((ext_vector_type(4)));

__device__ __forceinline__ float b2f(u16 u) {
    union { float f; u32 i; } x; x.i = ((u32)u) << 16; return x.f;
}
__device__ __forceinline__ u16 f2b(float f) {
    union { float f; u32 i; } x; x.f = f;
    u32 r = (x.i + 0x7fffu + ((x.i >> 16) & 1u)) >> 16;
    return (u16)r;
}
__device__ __forceinline__ float silu(float v) {
    return v * __builtin_amdgcn_rcpf(1.0f + __expf(-v));
}
__device__ __forceinline__ void fma4(float4 w, float4 s, float& acc) {
    acc = fmaf(w.x, s.x, acc);
    acc = fmaf(w.y, s.y, acc);
    acc = fmaf(w.z, s.z, acc);
    acc = fmaf(w.w, s.w, acc);
}

// ---------------- sort by dst (counting sort) ----------------
__global__ __launch_bounds__(256) void k_hist(const int* __restrict__ ei, int* __restrict__ hist) {
    int e = blockIdx.x * 256 + threadIdx.x;
    atomicAdd(&hist[ei[NEDGES + e]], 1);
}

__global__ __launch_bounds__(1024) void k_scan(const int* __restrict__ hist,
                                               int* __restrict__ row_ptr,
                                               int* __restrict__ cursor) {
    __shared__ int psum[1024];
    int t = threadIdx.x;
    int base = t * 20;
    int s = 0;
    if (base < NNODES)
        for (int i = 0; i < 20; ++i) s += hist[base + i];
    psum[t] = s;
    __syncthreads();
    for (int off = 1; off < 1024; off <<= 1) {
        int v = (t >= off) ? psum[t - off] : 0;
        __syncthreads();
        psum[t] += v;
        __syncthreads();
    }
    int excl = psum[t] - s;
    if (base < NNODES) {
        int run = excl;
        for (int i = 0; i < 20; ++i) {
            row_ptr[base + i] = run;
            cursor[base + i] = run;
            run += hist[base + i];
        }
    }
    if (t == 1023) row_ptr[NNODES] = psum[1023];
}

__global__ __launch_bounds__(256) void k_scatter(const int* __restrict__ ei, int* __restrict__ cursor,
                                                 int* __restrict__ ssrc, int* __restrict__ sdst) {
    int e = blockIdx.x * 256 + threadIdx.x;
    int d = ei[NEDGES + e];
    int pos = atomicAdd(&cursor[d], 1);
    ssrc[pos] = ei[e];
    sdst[pos] = d;
}

// ---------------- rbf-part W1 (rows 256..271) + b1 -> bf16 B-frag layout ----------------
__global__ __launch_bounds__(256) void k_prep_wr(const float* __restrict__ pmw1,
                                                 const float* __restrict__ pmb1,
                                                 u16* __restrict__ Wr) {
    int id = blockIdx.x * 256 + threadIdx.x;   // 1536 total
    if (id >= 1536) return;
    int l = id / 512; int r = id - l * 512;
    int nt = r >> 6, lane = r & 63;
    int col = nt * 16 + (lane & 15);
    alignas(16) u16 tmp[8];
    #pragma unroll
    for (int jj = 0; jj < 8; ++jj) {
        int kk = (lane >> 4) * 8 + jj;
        float v = 0.f;
        if (kk < 16) v = pmw1[l * 34816 + (256 + kk) * 128 + col];
        else if (kk == 16) v = pmb1[l * 128 + col];
        tmp[jj] = f2b(v);
    }
    *(uint4*)(Wr + (size_t)id * 8) = *(const uint4*)tmp;
}

// ---------------- Ysrc/Ydst weights (W1 rows 0..255) -> bf16 B-frag layout ----------------
// Yw layout: [l(3)][mat(2)][kc(4)][nt(8)][lane(64)][8]
__global__ __launch_bounds__(256) void k_prep_yw(const float* __restrict__ pmw1,
                                                 u16* __restrict__ Yw) {
    int id = blockIdx.x * 256 + threadIdx.x;   // 12288 total
    if (id >= 12288) return;
    int lane = id & 63;
    int g = id >> 6;
    int nt = g & 7; g >>= 3;
    int kc = g & 3; g >>= 2;
    int mat = g & 1; int l = g >> 1;
    int col = nt * 16 + (lane & 15);
    int kb = kc * 32 + ((lane >> 4) & 3) * 8;
    alignas(16) u16 tmp[8];
    #pragma unroll
    for (int jj = 0; jj < 8; ++jj)
        tmp[jj] = f2b(pmw1[(size_t)l * 34816 + (mat * 128 + kb + jj) * 128 + col]);
    *(uint4*)(Yw + (size_t)id * 8) = *(const uint4*)tmp;
}

// ---------------- pack fp32 [K][128] -> [K/4][128][4] ----------------
struct PackM { const float* s[11]; float* d[11]; int K[11]; };
__global__ __launch_bounds__(256) void k_pack(PackM pm) {
    int m = blockIdx.y;
    int idx = blockIdx.x * 256 + threadIdx.x;
    if (idx >= pm.K[m] * 128) return;
    int k = idx >> 7, j = idx & 127;
    pm.d[m][(k >> 2) * 512 + j * 4 + (k & 3)] = pm.s[m][idx];
}

// ---------------- prep: M = W2 @ V1b (per layer, packed) and bv = b2 @ V1b ----------------
__global__ __launch_bounds__(256) void k_prep_m(const float* __restrict__ pmw2,
        const float* __restrict__ pmb2, const float* __restrict__ V1p,
        float* __restrict__ Mp, float* __restrict__ bvv) {
    const int l = blockIdx.y, bx = blockIdx.x;
    const float* V1 = V1p + (size_t)l * 32768;
    const int tid = threadIdx.x;
    const int w = tid >> 6, lane = tid & 63;
    const int cg = lane & 15, ng = lane >> 4;
    const int jc0 = w * 32 + cg * 2, jc1 = jc0 + 1;
    __shared__ alignas(16) float W2L[16][PITCH];
    __shared__ float b2L[128];
    if (bx < 8) {
        const float4* src = (const float4*)(pmw2 + (size_t)l * 16384 + bx * 16 * 128);
        for (int q = tid; q < 512; q += 256) {
            int row = q >> 5, part = q & 31;
            *(float4*)&W2L[row][part * 4] = src[q];
        }
        __syncthreads();
        int r0 = ng * 4;
        float acc[4][2];
        #pragma unroll
        for (int n = 0; n < 4; ++n) { acc[n][0] = 0.f; acc[n][1] = 0.f; }
        for (int mm = 0; mm < 32; ++mm) {
            float4 wa = *(const float4*)(V1 + (32 + mm) * 512 + jc0 * 4);
            float4 wb = *(const float4*)(V1 + (32 + mm) * 512 + jc1 * 4);
            #pragma unroll
            for (int n = 0; n < 4; ++n) {
                float4 s4 = *(const float4*)&W2L[r0 + n][mm * 4];
                fma4(wa, s4, acc[n][0]);
                fma4(wb, s4, acc[n][1]);
            }
        }
        #pragma unroll
        for (int n = 0; n < 4; ++n) {
            int kg = bx * 16 + r0 + n;
            Mp[(size_t)l * 16384 + (kg >> 2) * 512 + jc0 * 4 + (kg & 3)] = acc[n][0];
            Mp[(size_t)l * 16384 + (kg >> 2) * 512 + jc1 * 4 + (kg & 3)] = acc[n][1];
        }
    } else {
        if (tid < 128) b2L[tid] = pmb2[l * 128 + tid];
        __syncthreads();
        if (ng == 0) {
            float a0 = 0.f, a1 = 0.f;
            for (int mm = 0; mm < 32; ++mm) {
                float4 wa = *(const float4*)(V1 + (32 + mm) * 512 + jc0 * 4);
                float4 wb = *(const float4*)(V1 + (32 + mm) * 512 + jc1 * 4);
                float4 s4 = *(const float4*)&b2L[mm * 4];
                fma4(wa, s4, a0);
                fma4(wb, s4, a1);
            }
            bvv[l * 128 + jc0] = a0;
            bvv[l * 128 + jc1] = a1;
        }
    }
}

// ---------------- time embedding -> te -> base1 ----------------
__global__ __launch_bounds__(128) void k_time(const int* __restrict__ tptr,
        const float* __restrict__ tw1, const float* __restrict__ tb1,
        const float* __restrict__ tw2, const float* __restrict__ tb2,
        const float* __restrict__ nw1, const float* __restrict__ nb1,
        float* __restrict__ base1) {
    __shared__ float emb[128], hid[128], te[128];
    int j = threadIdx.x;
    int raw = tptr[0];
    float tv;
    if (raw >= 0 && raw < (1 << 24)) tv = (float)raw;
    else tv = __int_as_float(raw);
    float fr = expf(-9.210340371976184f * (float)(j & 63) / 63.0f);
    float a = tv * fr;
    emb[j] = (j < 64) ? sinf(a) : cosf(a);
    __syncthreads();
    float acc = tb1[j];
    for (int k = 0; k < 128; ++k) acc += emb[k] * tw1[k * 128 + j];
    hid[j] = silu(acc);
    __syncthreads();
    acc = tb2[j];
    for (int k = 0; k < 128; ++k) acc += hid[k] * tw2[k * 128 + j];
    te[j] = acc;
    __syncthreads();
    acc = nb1[j];
    for (int k = 0; k < 128; ++k) acc += te[k] * nw1[(3 + k) * 128 + j];
    base1[j] = acc;
}

// ---------------- input node MLP + MFMA Ysrc/Ydst ----------------
__global__ __launch_bounds__(256) void k_h0(const float* __restrict__ x, const float* __restrict__ base1,
        const float* __restrict__ nw1, const float* __restrict__ nw2p, const float* __restrict__ nb2,
        const u16* __restrict__ Yw,
        float* __restrict__ hf, u16* __restrict__ Ysrc, u16* __restrict__ Ydst) {
    const int tid = threadIdx.x;
    const int w = tid >> 6, lane = tid & 63;
    const int cg = lane & 15, ng = lane >> 4;
    const int jc0 = w * 32 + cg * 2, jc1 = jc0 + 1;
    const int n0 = ng * 4;
    const int base = blockIdx.x * 16;
    __shared__ alignas(16) float xl[16][4];
    __shared__ alignas(16) float hid[16][PITCH];
    __shared__ alignas(16) u16 hb16[16 * BPITCH];
    if (tid < 48) { int n = tid / 3, cc = tid - n * 3; xl[n][cc] = x[(size_t)(base + n) * 3 + cc]; }
    __syncthreads();
    {
        float w0a = nw1[jc0], w0b = nw1[jc1];
        float w1a = nw1[128 + jc0], w1b = nw1[128 + jc1];
        float w2a = nw1[256 + jc0], w2b = nw1[256 + jc1];
        float ba = base1[jc0], bb = base1[jc1];
        #pragma unroll
        for (int n = 0; n < 4; ++n) {
            int row = n0 + n;
            float x0 = xl[row][0], x1 = xl[row][1], x2 = xl[row][2];
            float2 v;
            v.x = silu(ba + x0 * w0a + x1 * w1a + x2 * w2a);
            v.y = silu(bb + x0 * w0b + x1 * w1b + x2 * w2b);
            *(float2*)&hid[row][jc0] = v;
        }
    }
    __syncthreads();
    float acc[4][2];
    {
        float ba = nb2[jc0], bb = nb2[jc1];
        #pragma unroll
        for (int n = 0; n < 4; ++n) { acc[n][0] = ba; acc[n][1] = bb; }
        for (int kk = 0; kk < 32; ++kk) {
            float4 wa = *(const float4*)(nw2p + kk * 512 + jc0 * 4);
            float4 wb = *(const float4*)(nw2p + kk * 512 + jc1 * 4);
            #pragma unroll
            for (int n = 0; n < 4; ++n) {
                float4 s4 = *(const float4*)&hid[n0 + n][kk * 4];
                fma4(wa, s4, acc[n][0]);
                fma4(wb, s4, acc[n][1]);
            }
        }
    }
    __syncthreads();   // all reads of hid done
    #pragma unroll
    for (int n = 0; n < 4; ++n) {
        int row = n0 + n;
        *(float2*)&hf[(size_t)(base + row) * 128 + jc0] = make_float2(acc[n][0], acc[n][1]);
        *(u32*)&hb16[row * BPITCH + jc0] = (u32)f2b(acc[n][0]) | ((u32)f2b(acc[n][1]) << 16);
    }
    __syncthreads();
    // MFMA Y-GEMMs: wave w -> mat = w>>1, nt-half = w&1
    {
        const int mat = w >> 1, half = w & 1;
        const int lrow = lane & 15, quad = lane >> 4;
        bf16x8 a[4];
        #pragma unroll
        for (int kc = 0; kc < 4; ++kc)
            a[kc] = *(const bf16x8*)(hb16 + lrow * BPITCH + kc * 32 + quad * 8);
        u16* dst = mat ? Ydst : Ysrc;
        #pragma unroll
        for (int t = 0; t < 4; ++t) {
            int nt = half * 4 + t;
            f32x4 a4 = {0.f, 0.f, 0.f, 0.f};
            #pragma unroll
            for (int kc = 0; kc < 4; ++kc) {
                bf16x8 b = *(const bf16x8*)(Yw + (size_t)(((mat * 4 + kc) * 8 + nt) * 512 + lane * 8));
                a4 = __builtin_amdgcn_mfma_f32_16x16x32_bf16(a[kc], b, a4, 0, 0, 0);
            }
            #pragma unroll
            for (int r = 0; r < 4; ++r)
                dst[(size_t)(base + quad * 4 + r) * 128 + nt * 16 + lrow] = f2b(a4[r]);
        }
    }
}

// ---------------- edge kernel v5: fused MFMA + register epilogue (no sst round-trip) ----------------
// Lane (quad,lrow) holds 4 CONSECUTIVE sorted edges of one column -> segment-reduce in registers.
__global__ __launch_bounds__(512, 8) void k_edge(
        const u16* __restrict__ Ysrc, const u16* __restrict__ Ydst,
        const float* __restrict__ x,
        const int* __restrict__ ssrc, const int* __restrict__ sdst,
        const u16* __restrict__ Wr,
        float* __restrict__ s_glob) {
    __shared__ alignas(16) u16 ys[64 * BPITCH];   // staged Ysrc rows, pitch 136
    __shared__ float rv[64];
    __shared__ int s_d[64];
    __shared__ int s_s[64];
    const int tid = threadIdx.x;
    const int e0 = blockIdx.x * 64;
    if (tid < 64) {
        int s = ssrc[e0 + tid], d = sdst[e0 + tid];
        s_s[tid] = s; s_d[tid] = d;
        float ddx = x[s * 3] - x[d * 3];
        float ddy = x[s * 3 + 1] - x[d * 3 + 1];
        rv[tid] = sqrtf(ddx * ddx + ddy * ddy + 1e-8f);
    }
    __syncthreads();
    // stage Ysrc rows: 1024 x 16B chunks over 512 threads
    #pragma unroll
    for (int i = 0; i < 2; ++i) {
        int cch = tid + i * 512;
        int e = cch >> 4, part = cch & 15;
        *(uint4*)(ys + e * BPITCH + part * 8) = *(const uint4*)(Ysrc + (size_t)s_s[e] * 128 + part * 8);
    }
    const int w = tid >> 6, lane = tid & 63;
    const int m = w & 3, nh = w >> 2;
    const int lrow = lane & 15, quad = lane >> 4;
    float r = rv[m * 16 + lrow];
    union { bf16x8 v; u16 u[8]; } af;
    #pragma unroll
    for (int j = 0; j < 8; ++j) {
        int kk = quad * 8 + j;
        float v;
        if (kk < 16) {
            float dd = r - SQRT2 * (float)kk / 15.0f;
            v = __expf(-RBF_GAMMA * dd * dd);
        } else v = (kk == 16) ? 1.0f : 0.0f;
        af.u[j] = f2b(v);
    }
    __syncthreads();   // ys fully staged
    const int R = m * 16 + quad * 4;     // this lane's 4 consecutive edges
    const int d0 = s_d[R], d3 = s_d[R + 3];
    const u16* Bp = Wr + lane * 8;
    #pragma unroll
    for (int t = 0; t < 4; ++t) {
        int nt = nh * 4 + t;
        f32x4 a4 = {0.f, 0.f, 0.f, 0.f};
        bf16x8 b = *(const bf16x8*)(Bp + nt * 512);
        a4 = __builtin_amdgcn_mfma_f32_16x16x32_bf16(af.v, b, a4, 0, 0, 0);
        int col = nt * 16 + lrow;
        if (d0 == d3) {   // whole 4-edge group in one dst segment (common: deg ~32)
            float yd = b2f(Ydst[(size_t)d0 * 128 + col]);
            float s = 0.f;
            #pragma unroll
            for (int i2 = 0; i2 < 4; ++i2) {
                float v = a4[i2] + b2f(ys[(R + i2) * BPITCH + col]) + yd;
                s += silu(v);
            }
            atomicAdd(&s_glob[(size_t)d0 * 128 + col], s);
        } else {          // boundary inside group (rare): per-edge atomics
            #pragma unroll
            for (int i2 = 0; i2 < 4; ++i2) {
                int di = s_d[R + i2];
                float v = a4[i2] + b2f(ys[(R + i2) * BPITCH + col]) + b2f(Ydst[(size_t)di * 128 + col]);
                atomicAdd(&s_glob[(size_t)di * 128 + col], silu(v));
            }
        }
    }
}

// ---------------- node update: M-folded + MFMA Ysrc/Ydst ----------------
__global__ __launch_bounds__(256) void k_node(float* __restrict__ s_glob, const int* __restrict__ row_ptr,
        float* __restrict__ hf,
        const float* __restrict__ Mp, const float* __restrict__ V1p, const float* __restrict__ V2p,
        const float* __restrict__ bv, const float* __restrict__ c1, const float* __restrict__ c2,
        const float* __restrict__ lng, const float* __restrict__ lnb,
        const u16* __restrict__ Yw,
        u16* __restrict__ Ysrc, u16* __restrict__ Ydst) {
    const int tid = threadIdx.x;
    const int w = tid >> 6, lane = tid & 63;
    const int cg = lane & 15, ng = lane >> 4;
    const int jc0 = w * 32 + cg * 2, jc1 = jc0 + 1;
    const int n0 = ng * 4;
    const int base = blockIdx.x * 16;
    __shared__ alignas(16) float sv[16][PITCH], hv[16][PITCH];
    __shared__ alignas(16) u16 ybf[16 * BPITCH];
    __shared__ float mv[16][2];
    __shared__ int rp[17];
    float (*uv)[PITCH] = sv;   // uv overwrites sv (dead after GEMM2')
    float (*xs)[PITCH] = sv;   // xs overwrites uv (dead after GEMM3)

    if (tid < 17) rp[tid] = row_ptr[base + tid];
    {
        const float4* sg4 = (const float4*)(s_glob + (size_t)base * 128);
        float4* sg4w = (float4*)(s_glob + (size_t)base * 128);
        const float4* hg4 = (const float4*)(hf + (size_t)base * 128);
        for (int q = tid; q < 512; q += 256) {
            int row = q >> 5, part = q & 31;
            *(float4*)&sv[row][part * 4] = sg4[q];
            *(float4*)&hv[row][part * 4] = hg4[q];
            sg4w[q] = make_float4(0.f, 0.f, 0.f, 0.f);   // pre-zero for next layer's k_edge
        }
    }
    __syncthreads();

    float acc[4][2];
    // ---- GEMM2': u_pre = hv@V1a + sv@M + deg*bv + c1 ----
    {
        float ba = c1[jc0], bb = c1[jc1];
        float bva = bv[jc0], bvb = bv[jc1];
        #pragma unroll
        for (int n = 0; n < 4; ++n) {
            float dg = (float)(rp[n0 + n + 1] - rp[n0 + n]);
            acc[n][0] = ba + dg * bva; acc[n][1] = bb + dg * bvb;
        }
        for (int kk = 0; kk < 32; ++kk) {
            float4 wa = *(const float4*)(V1p + kk * 512 + jc0 * 4);
            float4 wb = *(const float4*)(V1p + kk * 512 + jc1 * 4);
            #pragma unroll
            for (int n = 0; n < 4; ++n) {
                float4 s4 = *(const float4*)&hv[n0 + n][kk * 4];
                fma4(wa, s4, acc[n][0]);
                fma4(wb, s4, acc[n][1]);
            }
        }
        for (int kk = 0; kk < 32; ++kk) {
            float4 wa = *(const float4*)(Mp + kk * 512 + jc0 * 4);
            float4 wb = *(const float4*)(Mp + kk * 512 + jc1 * 4);
            #pragma unroll
            for (int n = 0; n < 4; ++n) {
                float4 s4 = *(const float4*)&sv[n0 + n][kk * 4];
                fma4(wa, s4, acc[n][0]);
                fma4(wb, s4, acc[n][1]);
            }
        }
    }
    __syncthreads();   // all sv reads done
    #pragma unroll
    for (int n = 0; n < 4; ++n)
        *(float2*)&uv[n0 + n][jc0] = make_float2(silu(acc[n][0]), silu(acc[n][1]));
    __syncthreads();   // uv ready
    // ---- GEMM3: o = uv @ V2 + c2 ; xj = hv + o ----
    {
        float ba = c2[jc0], bb = c2[jc1];
        #pragma unroll
        for (int n = 0; n < 4; ++n) { acc[n][0] = ba; acc[n][1] = bb; }
        for (int kk = 0; kk < 32; ++kk) {
            float4 wa = *(const float4*)(V2p + kk * 512 + jc0 * 4);
            float4 wb = *(const float4*)(V2p + kk * 512 + jc1 * 4);
            #pragma unroll
            for (int n = 0; n < 4; ++n) {
                float4 s4 = *(const float4*)&uv[n0 + n][kk * 4];
                fma4(wa, s4, acc[n][0]);
                fma4(wb, s4, acc[n][1]);
            }
        }
        #pragma unroll
        for (int n = 0; n < 4; ++n) {
            float2 h2 = *(const float2*)&hv[n0 + n][jc0];
            acc[n][0] += h2.x; acc[n][1] += h2.y;
        }
    }
    __syncthreads();   // all uv reads done; safe to overwrite with xs
    #pragma unroll
    for (int n = 0; n < 4; ++n)
        *(float2*)&xs[n0 + n][jc0] = make_float2(acc[n][0], acc[n][1]);
    __syncthreads();
    // ---- LN reduce ----
    {
        int row = tid >> 4, part = tid & 15;
        float4 a = *(const float4*)&xs[row][part * 8];
        float4 b = *(const float4*)&xs[row][part * 8 + 4];
        float s1 = a.x + a.y + a.z + a.w + b.x + b.y + b.z + b.w;
        float s2 = a.x * a.x + a.y * a.y + a.z * a.z + a.w * a.w
                 + b.x * b.x + b.y * b.y + b.z * b.z + b.w * b.w;
        #pragma unroll
        for (int mq = 1; mq < 16; mq <<= 1) {
            s1 += __shfl_xor(s1, mq, 64);
            s2 += __shfl_xor(s2, mq, 64);
        }
        if (part == 0) { mv[row][0] = s1; mv[row][1] = s2; }
    }
    __syncthreads();
    // ---- LN apply (writes y to hf + bf16 tile for MFMA Y-GEMM) ----
    {
        float ga = lng[jc0], gb = lng[jc1];
        float bba = lnb[jc0], bbb = lnb[jc1];
        #pragma unroll
        for (int n = 0; n < 4; ++n) {
            int row = n0 + n;
            float mu = mv[row][0] * (1.0f / 128.0f);
            float var = mv[row][1] * (1.0f / 128.0f) - mu * mu;
            float rs = rsqrtf(var + 1e-5f);
            float y0 = (xs[row][jc0] - mu) * rs * ga + bba;
            float y1 = (xs[row][jc1] - mu) * rs * gb + bbb;
            *(float2*)&hf[(size_t)(base + row) * 128 + jc0] = make_float2(y0, y1);
            *(u32*)&ybf[row * BPITCH + jc0] = (u32)f2b(y0) | ((u32)f2b(y1) << 16);
        }
    }
    if (Yw != nullptr) {
        __syncthreads();
        const int mat = w >> 1, half = w & 1;
        const int lrow = lane & 15, quad = lane >> 4;
        bf16x8 a[4];
        #pragma unroll
        for (int kc = 0; kc < 4; ++kc)
            a[kc] = *(const bf16x8*)(ybf + lrow * BPITCH + kc * 32 + quad * 8);
        u16* dst = mat ? Ydst : Ysrc;
        #pragma unroll
        for (int t = 0; t < 4; ++t) {
            int nt = half * 4 + t;
            f32x4 a4 = {0.f, 0.f, 0.f, 0.f};
            #pragma unroll
            for (int kc = 0; kc < 4; ++kc) {
                bf16x8 b = *(const bf16x8*)(Yw + (size_t)(((mat * 4 + kc) * 8 + nt) * 512 + lane * 8));
                a4 = __builtin_amdgcn_mfma_f32_16x16x32_bf16(a[kc], b, a4, 0, 0, 0);
            }
            #pragma unroll
            for (int r = 0; r < 4; ++r)
                dst[(size_t)(base + quad * 4 + r) * 128 + nt * 16 + lrow] = f2b(a4[r]);
        }
    }
}

// ---------------- output MLP (fp32 out, padded LDS) ----------------
__global__ __launch_bounds__(256) void k_out(const float* __restrict__ hf, const float* __restrict__ ow1p,
        const float* __restrict__ ob1, const float* __restrict__ ow2, const float* __restrict__ ob2,
        float* __restrict__ out) {
    const int tid = threadIdx.x;
    const int w = tid >> 6, lane = tid & 63;
    const int cg = lane & 15, ng = lane >> 4;
    const int jc0 = w * 32 + cg * 2, jc1 = jc0 + 1;
    const int n0 = ng * 4;
    const int base = blockIdx.x * 16;
    __shared__ alignas(16) float hv[16][PITCH];
    __shared__ float hid[16][PITCH];
    for (int q = tid; q < 512; q += 256) {
        int row = q >> 5, part = q & 31;
        *(float4*)&hv[row][part * 4] = ((const float4*)(hf + (size_t)base * 128))[q];
    }
    __syncthreads();
    float acc[4][2];
    {
        float ba = ob1[jc0], bb = ob1[jc1];
        #pragma unroll
        for (int n = 0; n < 4; ++n) { acc[n][0] = ba; acc[n][1] = bb; }
    }
    for (int kk = 0; kk < 32; ++kk) {
        float4 wa = *(const float4*)(ow1p + kk * 512 + jc0 * 4);
        float4 wb = *(const float4*)(ow1p + kk * 512 + jc1 * 4);
        #pragma unroll
        for (int n = 0; n < 4; ++n) {
            float4 s4 = *(const float4*)&hv[n0 + n][kk * 4];
            fma4(wa, s4, acc[n][0]);
            fma4(wb, s4, acc[n][1]);
        }
    }
    #pragma unroll
    for (int n = 0; n < 4; ++n) {
        hid[n0 + n][jc0] = silu(acc[n][0]);
        hid[n0 + n][jc1] = silu(acc[n][1]);
    }
    __syncthreads();
    if (tid < 48) {
        int n = tid / 3, cc = tid - n * 3;
        float o = ob2[cc];
        for (int k = 0; k < 128; ++k) o += hid[n][k] * ow2[k * 3 + cc];
        out[(size_t)(base + n) * 3 + cc] = o;
    }
}

extern "C" void kernel_launch(void* const* d_in, const int* in_sizes, int n_in,
                              void* d_out, int out_size, void* d_ws, size_t ws_size,
                              hipStream_t stream) {
    const float* x    = (const float*)d_in[0];
    const int* ei     = (const int*)d_in[1];
    const int* tptr   = (const int*)d_in[2];
    const float* tw1  = (const float*)d_in[3];
    const float* tb1  = (const float*)d_in[4];
    const float* tw2  = (const float*)d_in[5];
    const float* tb2  = (const float*)d_in[6];
    const float* nw1  = (const float*)d_in[7];
    const float* nb1  = (const float*)d_in[8];
    const float* nw2  = (const float*)d_in[9];
    const float* nb2  = (const float*)d_in[10];
    const float* pmw1 = (const float*)d_in[11];
    const float* pmb1 = (const float*)d_in[12];
    const float* pmw2 = (const float*)d_in[13];
    const float* pmb2 = (const float*)d_in[14];
    const float* phw1 = (const float*)d_in[15];
    const float* phb1 = (const float*)d_in[16];
    const float* phw2 = (const float*)d_in[17];
    const float* phb2 = (const float*)d_in[18];
    const float* lng  = (const float*)d_in[19];
    const float* lnb  = (const float*)d_in[20];
    const float* ow1  = (const float*)d_in[21];
    const float* ob1  = (const float*)d_in[22];
    const float* ow2  = (const float*)d_in[23];
    const float* ob2  = (const float*)d_in[24];
    float* out = (float*)d_out;

    char* wsp = (char*)d_ws;
    size_t off = 0;
    auto alloc = [&](size_t bytes) -> void* {
        void* p = wsp + off;
        off += (bytes + 255) & ~(size_t)255;
        return p;
    };
    int* hist    = (int*)alloc((size_t)NNODES * 4);
    int* cursor  = (int*)alloc((size_t)NNODES * 4);
    int* row_ptr = (int*)alloc((size_t)(NNODES + 1) * 4);
    int* ssrc    = (int*)alloc((size_t)NEDGES * 4);
    int* sdst    = (int*)alloc((size_t)NEDGES * 4);
    u16* Wr      = (u16*)alloc((size_t)3 * 8 * 64 * 8 * 2);
    u16* Yw      = (u16*)alloc((size_t)3 * 2 * 4 * 8 * 64 * 8 * 2);
    float* base1 = (float*)alloc(128 * 4);
    float* V1p   = (float*)alloc((size_t)3 * 256 * 128 * 4);
    float* V2p   = (float*)alloc((size_t)3 * 128 * 128 * 4);
    float* nw2p  = (float*)alloc((size_t)128 * 128 * 4);
    float* ow1p  = (float*)alloc((size_t)128 * 128 * 4);
    float* W2p   = (float*)alloc((size_t)3 * 128 * 128 * 4);
    float* Mp    = (float*)alloc((size_t)3 * 128 * 128 * 4);
    float* bvv   = (float*)alloc((size_t)3 * 128 * 4);
    float* hf    = (float*)alloc((size_t)NNODES * 128 * 4);
    u16* Ysrc    = (u16*)alloc((size_t)NNODES * 128 * 2);
    u16* Ydst    = (u16*)alloc((size_t)NNODES * 128 * 2);
    float* s_glob= (float*)alloc((size_t)NNODES * 128 * 4);

    (void)hipMemsetAsync(hist, 0, (size_t)NNODES * 4, stream);
    k_hist<<<NEDGES / 256, 256, 0, stream>>>(ei, hist);
    k_scan<<<1, 1024, 0, stream>>>(hist, row_ptr, cursor);
    k_scatter<<<NEDGES / 256, 256, 0, stream>>>(ei, cursor, ssrc, sdst);
    k_prep_wr<<<6, 256, 0, stream>>>(pmw1, pmb1, Wr);
    k_prep_yw<<<48, 256, 0, stream>>>(pmw1, Yw);

    PackM pm;
    for (int l = 0; l < 3; ++l) {
        pm.s[l] = pmw2 + (size_t)l * 16384;      pm.d[l] = W2p + (size_t)l * 16384;  pm.K[l] = 128;
        pm.s[3 + l] = phw2 + (size_t)l * 16384;  pm.d[3 + l] = V2p + (size_t)l * 16384; pm.K[3 + l] = 128;
        pm.s[6 + l] = phw1 + (size_t)l * 32768;  pm.d[6 + l] = V1p + (size_t)l * 32768; pm.K[6 + l] = 256;
    }
    pm.s[9] = nw2;  pm.d[9] = nw2p;  pm.K[9] = 128;
    pm.s[10] = ow1; pm.d[10] = ow1p; pm.K[10] = 128;
    k_pack<<<dim3(128, 11), 256, 0, stream>>>(pm);
    k_prep_m<<<dim3(9, 3), 256, 0, stream>>>(pmw2, pmb2, V1p, Mp, bvv);

    k_time<<<1, 128, 0, stream>>>(tptr, tw1, tb1, tw2, tb2, nw1, nb1, base1);
    k_h0<<<1250, 256, 0, stream>>>(x, base1, nw1, nw2p, nb2, Yw, hf, Ysrc, Ydst);

    // s_glob zeroed once here; k_node re-zeroes it for the next layer after reading
    (void)hipMemsetAsync(s_glob, 0, (size_t)NNODES * 128 * 4, stream);
    for (int l = 0; l < 3; ++l) {
        k_edge<<<NEDGES / 64, 512, 0, stream>>>(Ysrc, Ydst, x, ssrc, sdst,
                Wr + (size_t)l * 4096, s_glob);
        const u16* YwN = (l < 2) ? (Yw + (size_t)(l + 1) * 32768) : nullptr;
        k_node<<<1250, 256, 0, stream>>>(s_glob, row_ptr, hf,
                Mp + (size_t)l * 16384, V1p + (size_t)l * 32768, V2p + (size_t)l * 16384,
                bvv + l * 128, phb1 + l * 128, phb2 + l * 128, lng + l * 128, lnb + l * 128,
                YwN, Ysrc, Ydst);
    }
    k_out<<<1250, 256, 0, stream>>>(hf, ow1p, ob1, ow2, ob2, out);
}

// Round 15
// 575.933 us; speedup vs baseline: 1.8491x; 1.8491x over previous
//
#include <hip/hip_runtime.h>

typedef unsigned short u16;
typedef unsigned int u32;

#define NNODES 20000
#define NEDGES 640000
// GAMMA = 1/(2*(sqrt(2)/15)^2) = 56.25 exactly
#define RBF_GAMMA 56.25f
#define SQRT2 1.4142135623730951f
#define PITCH 132    // fp32 LDS row pitch
#define BPITCH 136   // bf16 LDS row pitch (u16)

typedef __bf16 bf16x8 __attribute__((ext_vector_type(8)));
typedef __bf16 bf16x2 __attribute__((ext_vector_type(2)));
typedef float f32x4 __attribute__((ext_vector_type(4)));

__device__ __forceinline__ float b2f(u16 u) {
    union { float f; u32 i; } x; x.i = ((u32)u) << 16; return x.f;
}
__device__ __forceinline__ float hi2f(u32 w) {
    union { float f; u32 i; } x; x.i = w & 0xffff0000u; return x.f;
}
__device__ __forceinline__ float lo2f(u32 w) {
    union { float f; u32 i; } x; x.i = w << 16; return x.f;
}
__device__ __forceinline__ u16 f2b(float f) {
    union { float f; u32 i; } x; x.f = f;
    u32 r = (x.i + 0x7fffu + ((x.i >> 16) & 1u)) >> 16;
    return (u16)r;
}
// pack 2 fp32 -> 2 bf16 (RNE); single v_cvt_pk_bf16_f32 on gfx950
__device__ __forceinline__ u32 pack2(float a, float b) {
#if __has_builtin(__builtin_amdgcn_cvt_pk_bf16_f32)
    union { bf16x2 v; u32 u; } x;
    x.v = __builtin_amdgcn_cvt_pk_bf16_f32(a, b);
    return x.u;
#else
    return (u32)f2b(a) | ((u32)f2b(b) << 16);
#endif
}
__device__ __forceinline__ float silu(float v) {
    return v * __builtin_amdgcn_rcpf(1.0f + __expf(-v));
}
__device__ __forceinline__ void fma4(float4 w, float4 s, float& acc) {
    acc = fmaf(w.x, s.x, acc);
    acc = fmaf(w.y, s.y, acc);
    acc = fmaf(w.z, s.z, acc);
    acc = fmaf(w.w, s.w, acc);
}

// ---------------- sort by dst (counting sort) ----------------
__global__ __launch_bounds__(256) void k_hist(const int* __restrict__ ei, int* __restrict__ hist) {
    int e = blockIdx.x * 256 + threadIdx.x;
    atomicAdd(&hist[ei[NEDGES + e]], 1);
}

__global__ __launch_bounds__(1024) void k_scan(const int* __restrict__ hist,
                                               int* __restrict__ row_ptr,
                                               int* __restrict__ cursor) {
    __shared__ int psum[1024];
    int t = threadIdx.x;
    int base = t * 20;
    int s = 0;
    if (base < NNODES)
        for (int i = 0; i < 20; ++i) s += hist[base + i];
    psum[t] = s;
    __syncthreads();
    for (int off = 1; off < 1024; off <<= 1) {
        int v = (t >= off) ? psum[t - off] : 0;
        __syncthreads();
        psum[t] += v;
        __syncthreads();
    }
    int excl = psum[t] - s;
    if (base < NNODES) {
        int run = excl;
        for (int i = 0; i < 20; ++i) {
            row_ptr[base + i] = run;
            cursor[base + i] = run;
            run += hist[base + i];
        }
    }
    if (t == 1023) row_ptr[NNODES] = psum[1023];
}

__global__ __launch_bounds__(256) void k_scatter(const int* __restrict__ ei, int* __restrict__ cursor,
                                                 int* __restrict__ ssrc, int* __restrict__ sdst) {
    int e = blockIdx.x * 256 + threadIdx.x;
    int d = ei[NEDGES + e];
    int pos = atomicAdd(&cursor[d], 1);
    ssrc[pos] = ei[e];
    sdst[pos] = d;
}

// ---------------- rbf-part W1 (rows 256..271) + b1 -> bf16 B-frag layout ----------------
__global__ __launch_bounds__(256) void k_prep_wr(const float* __restrict__ pmw1,
                                                 const float* __restrict__ pmb1,
                                                 u16* __restrict__ Wr) {
    int id = blockIdx.x * 256 + threadIdx.x;   // 1536 total
    if (id >= 1536) return;
    int l = id / 512; int r = id - l * 512;
    int nt = r >> 6, lane = r & 63;
    int col = nt * 16 + (lane & 15);
    alignas(16) u16 tmp[8];
    #pragma unroll
    for (int jj = 0; jj < 8; ++jj) {
        int kk = (lane >> 4) * 8 + jj;
        float v = 0.f;
        if (kk < 16) v = pmw1[l * 34816 + (256 + kk) * 128 + col];
        else if (kk == 16) v = pmb1[l * 128 + col];
        tmp[jj] = f2b(v);
    }
    *(uint4*)(Wr + (size_t)id * 8) = *(const uint4*)tmp;
}

// ---------------- Ysrc/Ydst weights (W1 rows 0..255) -> bf16 B-frag layout ----------------
// Yw layout: [l(3)][mat(2)][kc(4)][nt(8)][lane(64)][8]
__global__ __launch_bounds__(256) void k_prep_yw(const float* __restrict__ pmw1,
                                                 u16* __restrict__ Yw) {
    int id = blockIdx.x * 256 + threadIdx.x;   // 12288 total
    if (id >= 12288) return;
    int lane = id & 63;
    int g = id >> 6;
    int nt = g & 7; g >>= 3;
    int kc = g & 3; g >>= 2;
    int mat = g & 1; int l = g >> 1;
    int col = nt * 16 + (lane & 15);
    int kb = kc * 32 + ((lane >> 4) & 3) * 8;
    alignas(16) u16 tmp[8];
    #pragma unroll
    for (int jj = 0; jj < 8; ++jj)
        tmp[jj] = f2b(pmw1[(size_t)l * 34816 + (mat * 128 + kb + jj) * 128 + col]);
    *(uint4*)(Yw + (size_t)id * 8) = *(const uint4*)tmp;
}

// ---------------- pack fp32 [K][128] -> [K/4][128][4] ----------------
struct PackM { const float* s[11]; float* d[11]; int K[11]; };
__global__ __launch_bounds__(256) void k_pack(PackM pm) {
    int m = blockIdx.y;
    int idx = blockIdx.x * 256 + threadIdx.x;
    if (idx >= pm.K[m] * 128) return;
    int k = idx >> 7, j = idx & 127;
    pm.d[m][(k >> 2) * 512 + j * 4 + (k & 3)] = pm.s[m][idx];
}

// ---------------- prep: M = W2 @ V1b (per layer, packed) and bv = b2 @ V1b ----------------
__global__ __launch_bounds__(256) void k_prep_m(const float* __restrict__ pmw2,
        const float* __restrict__ pmb2, const float* __restrict__ V1p,
        float* __restrict__ Mp, float* __restrict__ bvv) {
    const int l = blockIdx.y, bx = blockIdx.x;
    const float* V1 = V1p + (size_t)l * 32768;
    const int tid = threadIdx.x;
    const int w = tid >> 6, lane = tid & 63;
    const int cg = lane & 15, ng = lane >> 4;
    const int jc0 = w * 32 + cg * 2, jc1 = jc0 + 1;
    __shared__ alignas(16) float W2L[16][PITCH];
    __shared__ float b2L[128];
    if (bx < 8) {
        const float4* src = (const float4*)(pmw2 + (size_t)l * 16384 + bx * 16 * 128);
        for (int q = tid; q < 512; q += 256) {
            int row = q >> 5, part = q & 31;
            *(float4*)&W2L[row][part * 4] = src[q];
        }
        __syncthreads();
        int r0 = ng * 4;
        float acc[4][2];
        #pragma unroll
        for (int n = 0; n < 4; ++n) { acc[n][0] = 0.f; acc[n][1] = 0.f; }
        for (int mm = 0; mm < 32; ++mm) {
            float4 wa = *(const float4*)(V1 + (32 + mm) * 512 + jc0 * 4);
            float4 wb = *(const float4*)(V1 + (32 + mm) * 512 + jc1 * 4);
            #pragma unroll
            for (int n = 0; n < 4; ++n) {
                float4 s4 = *(const float4*)&W2L[r0 + n][mm * 4];
                fma4(wa, s4, acc[n][0]);
                fma4(wb, s4, acc[n][1]);
            }
        }
        #pragma unroll
        for (int n = 0; n < 4; ++n) {
            int kg = bx * 16 + r0 + n;
            Mp[(size_t)l * 16384 + (kg >> 2) * 512 + jc0 * 4 + (kg & 3)] = acc[n][0];
            Mp[(size_t)l * 16384 + (kg >> 2) * 512 + jc1 * 4 + (kg & 3)] = acc[n][1];
        }
    } else {
        if (tid < 128) b2L[tid] = pmb2[l * 128 + tid];
        __syncthreads();
        if (ng == 0) {
            float a0 = 0.f, a1 = 0.f;
            for (int mm = 0; mm < 32; ++mm) {
                float4 wa = *(const float4*)(V1 + (32 + mm) * 512 + jc0 * 4);
                float4 wb = *(const float4*)(V1 + (32 + mm) * 512 + jc1 * 4);
                float4 s4 = *(const float4*)&b2L[mm * 4];
                fma4(wa, s4, a0);
                fma4(wb, s4, a1);
            }
            bvv[l * 128 + jc0] = a0;
            bvv[l * 128 + jc1] = a1;
        }
    }
}

// ---------------- time embedding -> te -> base1 ----------------
__global__ __launch_bounds__(128) void k_time(const int* __restrict__ tptr,
        const float* __restrict__ tw1, const float* __restrict__ tb1,
        const float* __restrict__ tw2, const float* __restrict__ tb2,
        const float* __restrict__ nw1, const float* __restrict__ nb1,
        float* __restrict__ base1) {
    __shared__ float emb[128], hid[128], te[128];
    int j = threadIdx.x;
    int raw = tptr[0];
    float tv;
    if (raw >= 0 && raw < (1 << 24)) tv = (float)raw;
    else tv = __int_as_float(raw);
    float fr = expf(-9.210340371976184f * (float)(j & 63) / 63.0f);
    float a = tv * fr;
    emb[j] = (j < 64) ? sinf(a) : cosf(a);
    __syncthreads();
    float acc = tb1[j];
    for (int k = 0; k < 128; ++k) acc += emb[k] * tw1[k * 128 + j];
    hid[j] = silu(acc);
    __syncthreads();
    acc = tb2[j];
    for (int k = 0; k < 128; ++k) acc += hid[k] * tw2[k * 128 + j];
    te[j] = acc;
    __syncthreads();
    acc = nb1[j];
    for (int k = 0; k < 128; ++k) acc += te[k] * nw1[(3 + k) * 128 + j];
    base1[j] = acc;
}

// ---------------- input node MLP + MFMA Ysrc/Ydst ----------------
__global__ __launch_bounds__(256) void k_h0(const float* __restrict__ x, const float* __restrict__ base1,
        const float* __restrict__ nw1, const float* __restrict__ nw2p, const float* __restrict__ nb2,
        const u16* __restrict__ Yw,
        float* __restrict__ hf, u16* __restrict__ Ysrc, u16* __restrict__ Ydst) {
    const int tid = threadIdx.x;
    const int w = tid >> 6, lane = tid & 63;
    const int cg = lane & 15, ng = lane >> 4;
    const int jc0 = w * 32 + cg * 2, jc1 = jc0 + 1;
    const int n0 = ng * 4;
    const int base = blockIdx.x * 16;
    __shared__ alignas(16) float xl[16][4];
    __shared__ alignas(16) float hid[16][PITCH];
    __shared__ alignas(16) u16 hb16[16 * BPITCH];
    if (tid < 48) { int n = tid / 3, cc = tid - n * 3; xl[n][cc] = x[(size_t)(base + n) * 3 + cc]; }
    __syncthreads();
    {
        float w0a = nw1[jc0], w0b = nw1[jc1];
        float w1a = nw1[128 + jc0], w1b = nw1[128 + jc1];
        float w2a = nw1[256 + jc0], w2b = nw1[256 + jc1];
        float ba = base1[jc0], bb = base1[jc1];
        #pragma unroll
        for (int n = 0; n < 4; ++n) {
            int row = n0 + n;
            float x0 = xl[row][0], x1 = xl[row][1], x2 = xl[row][2];
            float2 v;
            v.x = silu(ba + x0 * w0a + x1 * w1a + x2 * w2a);
            v.y = silu(bb + x0 * w0b + x1 * w1b + x2 * w2b);
            *(float2*)&hid[row][jc0] = v;
        }
    }
    __syncthreads();
    float acc[4][2];
    {
        float ba = nb2[jc0], bb = nb2[jc1];
        #pragma unroll
        for (int n = 0; n < 4; ++n) { acc[n][0] = ba; acc[n][1] = bb; }
        for (int kk = 0; kk < 32; ++kk) {
            float4 wa = *(const float4*)(nw2p + kk * 512 + jc0 * 4);
            float4 wb = *(const float4*)(nw2p + kk * 512 + jc1 * 4);
            #pragma unroll
            for (int n = 0; n < 4; ++n) {
                float4 s4 = *(const float4*)&hid[n0 + n][kk * 4];
                fma4(wa, s4, acc[n][0]);
                fma4(wb, s4, acc[n][1]);
            }
        }
    }
    __syncthreads();   // all reads of hid done
    #pragma unroll
    for (int n = 0; n < 4; ++n) {
        int row = n0 + n;
        *(float2*)&hf[(size_t)(base + row) * 128 + jc0] = make_float2(acc[n][0], acc[n][1]);
        *(u32*)&hb16[row * BPITCH + jc0] = pack2(acc[n][0], acc[n][1]);
    }
    __syncthreads();
    // MFMA Y-GEMMs: wave w -> mat = w>>1, nt-half = w&1
    {
        const int mat = w >> 1, half = w & 1;
        const int lrow = lane & 15, quad = lane >> 4;
        bf16x8 a[4];
        #pragma unroll
        for (int kc = 0; kc < 4; ++kc)
            a[kc] = *(const bf16x8*)(hb16 + lrow * BPITCH + kc * 32 + quad * 8);
        u16* dst = mat ? Ydst : Ysrc;
        #pragma unroll
        for (int t = 0; t < 4; ++t) {
            int nt = half * 4 + t;
            f32x4 a4 = {0.f, 0.f, 0.f, 0.f};
            #pragma unroll
            for (int kc = 0; kc < 4; ++kc) {
                bf16x8 b = *(const bf16x8*)(Yw + (size_t)(((mat * 4 + kc) * 8 + nt) * 512 + lane * 8));
                a4 = __builtin_amdgcn_mfma_f32_16x16x32_bf16(a[kc], b, a4, 0, 0, 0);
            }
            #pragma unroll
            for (int r = 0; r < 4; ++r)
                dst[(size_t)(base + quad * 4 + r) * 128 + nt * 16 + lrow] = f2b(a4[r]);
        }
    }
}

// ---------------- edge kernel (round-13 proven): 512 threads, bf16 sst, 2x8-row epilogue ----------------
__global__ __launch_bounds__(512, 8) void k_edge(
        const u16* __restrict__ Ysrc, const u16* __restrict__ Ydst,
        const float* __restrict__ x,
        const int* __restrict__ ssrc, const int* __restrict__ sdst,
        const u16* __restrict__ Wr,
        float* __restrict__ s_glob) {
    __shared__ alignas(16) u16 sst[128 * 72];   // [col][row] bf16, pitch 72
    __shared__ alignas(16) u16 ys[64 * 128];    // staged Ysrc rows
    __shared__ float rv[64];
    __shared__ int s_d[65];
    __shared__ int s_s[64];
    const int tid = threadIdx.x;
    const int e0 = blockIdx.x * 64;
    if (tid < 64) {
        int s = ssrc[e0 + tid], d = sdst[e0 + tid];
        s_s[tid] = s; s_d[tid] = d;
        float ddx = x[s * 3] - x[d * 3];
        float ddy = x[s * 3 + 1] - x[d * 3 + 1];
        rv[tid] = sqrtf(ddx * ddx + ddy * ddy + 1e-8f);
    } else if (tid == 64) {
        s_d[64] = -1;
    }
    __syncthreads();
    #pragma unroll
    for (int i = 0; i < 2; ++i) {
        int cch = tid + i * 512;
        int e = cch >> 4, part = cch & 15;
        *(uint4*)(ys + e * 128 + part * 8) = *(const uint4*)(Ysrc + (size_t)s_s[e] * 128 + part * 8);
    }
    const int w = tid >> 6, lane = tid & 63;
    const int m = w & 3, nh = w >> 2;
    const int lrow = lane & 15, quad = lane >> 4;
    float r = rv[m * 16 + lrow];
    union { bf16x8 v; u16 u[8]; } af;
    #pragma unroll
    for (int j = 0; j < 8; ++j) {
        int kk = quad * 8 + j;
        float v;
        if (kk < 16) {
            float dd = r - SQRT2 * (float)kk / 15.0f;
            v = __expf(-RBF_GAMMA * dd * dd);
        } else v = (kk == 16) ? 1.0f : 0.0f;
        af.u[j] = f2b(v);
    }
    {
        const u16* Bp = Wr + lane * 8;
        #pragma unroll
        for (int t = 0; t < 4; ++t) {
            int nt = nh * 4 + t;
            f32x4 a4 = {0.f, 0.f, 0.f, 0.f};
            bf16x8 b = *(const bf16x8*)(Bp + nt * 512);
            a4 = __builtin_amdgcn_mfma_f32_16x16x32_bf16(af.v, b, a4, 0, 0, 0);
            int col = nt * 16 + lrow;
            u32 lo = pack2(a4[0], a4[1]);
            u32 hi = pack2(a4[2], a4[3]);
            *(uint2*)(sst + col * 72 + m * 16 + quad * 4) = make_uint2(lo, hi);
        }
    }
    __syncthreads();
    {
        const int col = tid & 127, q = tid >> 7;
        const int r0 = q * 16;
        float a = 0.f;
        int cd = s_d[r0];
        float yd = b2f(Ydst[(size_t)cd * 128 + col]);
        #pragma unroll
        for (int h = 0; h < 2; ++h) {
            uint4 c0 = *(const uint4*)(sst + col * 72 + r0 + h * 8);
            float sv8[8];
            sv8[0] = lo2f(c0.x); sv8[1] = hi2f(c0.x);
            sv8[2] = lo2f(c0.y); sv8[3] = hi2f(c0.y);
            sv8[4] = lo2f(c0.z); sv8[5] = hi2f(c0.z);
            sv8[6] = lo2f(c0.w); sv8[7] = hi2f(c0.w);
            #pragma unroll
            for (int i = 0; i < 8; ++i) {
                int rr = r0 + h * 8 + i;
                int nd = s_d[rr + 1];
                float v = sv8[i] + b2f(ys[rr * 128 + col]) + yd;
                a += silu(v);
                bool last = (h == 1 && i == 7);
                if (last || nd != cd) {
                    atomicAdd(&s_glob[(size_t)cd * 128 + col], a);
                    a = 0.f;
                    if (!last && nd != cd)
                        yd = b2f(Ydst[(size_t)nd * 128 + col]);
                }
                cd = nd;
            }
        }
    }
}

// ---------------- node update: M-folded + MFMA Ysrc/Ydst ----------------
__global__ __launch_bounds__(256) void k_node(float* __restrict__ s_glob, const int* __restrict__ row_ptr,
        float* __restrict__ hf,
        const float* __restrict__ Mp, const float* __restrict__ V1p, const float* __restrict__ V2p,
        const float* __restrict__ bv, const float* __restrict__ c1, const float* __restrict__ c2,
        const float* __restrict__ lng, const float* __restrict__ lnb,
        const u16* __restrict__ Yw,
        u16* __restrict__ Ysrc, u16* __restrict__ Ydst) {
    const int tid = threadIdx.x;
    const int w = tid >> 6, lane = tid & 63;
    const int cg = lane & 15, ng = lane >> 4;
    const int jc0 = w * 32 + cg * 2, jc1 = jc0 + 1;
    const int n0 = ng * 4;
    const int base = blockIdx.x * 16;
    __shared__ alignas(16) float sv[16][PITCH], hv[16][PITCH];
    __shared__ alignas(16) u16 ybf[16 * BPITCH];
    __shared__ float mv[16][2];
    __shared__ int rp[17];
    float (*uv)[PITCH] = sv;
    float (*xs)[PITCH] = sv;

    if (tid < 17) rp[tid] = row_ptr[base + tid];
    {
        const float4* sg4 = (const float4*)(s_glob + (size_t)base * 128);
        float4* sg4w = (float4*)(s_glob + (size_t)base * 128);
        const float4* hg4 = (const float4*)(hf + (size_t)base * 128);
        for (int q = tid; q < 512; q += 256) {
            int row = q >> 5, part = q & 31;
            *(float4*)&sv[row][part * 4] = sg4[q];
            *(float4*)&hv[row][part * 4] = hg4[q];
            sg4w[q] = make_float4(0.f, 0.f, 0.f, 0.f);
        }
    }
    __syncthreads();

    float acc[4][2];
    // ---- GEMM2': u_pre = hv@V1a + sv@M + deg*bv + c1 ----
    {
        float ba = c1[jc0], bb = c1[jc1];
        float bva = bv[jc0], bvb = bv[jc1];
        #pragma unroll
        for (int n = 0; n < 4; ++n) {
            float dg = (float)(rp[n0 + n + 1] - rp[n0 + n]);
            acc[n][0] = ba + dg * bva; acc[n][1] = bb + dg * bvb;
        }
        for (int kk = 0; kk < 32; ++kk) {
            float4 wa = *(const float4*)(V1p + kk * 512 + jc0 * 4);
            float4 wb = *(const float4*)(V1p + kk * 512 + jc1 * 4);
            #pragma unroll
            for (int n = 0; n < 4; ++n) {
                float4 s4 = *(const float4*)&hv[n0 + n][kk * 4];
                fma4(wa, s4, acc[n][0]);
                fma4(wb, s4, acc[n][1]);
            }
        }
        for (int kk = 0; kk < 32; ++kk) {
            float4 wa = *(const float4*)(Mp + kk * 512 + jc0 * 4);
            float4 wb = *(const float4*)(Mp + kk * 512 + jc1 * 4);
            #pragma unroll
            for (int n = 0; n < 4; ++n) {
                float4 s4 = *(const float4*)&sv[n0 + n][kk * 4];
                fma4(wa, s4, acc[n][0]);
                fma4(wb, s4, acc[n][1]);
            }
        }
    }
    __syncthreads();
    #pragma unroll
    for (int n = 0; n < 4; ++n)
        *(float2*)&uv[n0 + n][jc0] = make_float2(silu(acc[n][0]), silu(acc[n][1]));
    __syncthreads();
    // ---- GEMM3: o = uv @ V2 + c2 ; xj = hv + o ----
    {
        float ba = c2[jc0], bb = c2[jc1];
        #pragma unroll
        for (int n = 0; n < 4; ++n) { acc[n][0] = ba; acc[n][1] = bb; }
        for (int kk = 0; kk < 32; ++kk) {
            float4 wa = *(const float4*)(V2p + kk * 512 + jc0 * 4);
            float4 wb = *(const float4*)(V2p + kk * 512 + jc1 * 4);
            #pragma unroll
            for (int n = 0; n < 4; ++n) {
                float4 s4 = *(const float4*)&uv[n0 + n][kk * 4];
                fma4(wa, s4, acc[n][0]);
                fma4(wb, s4, acc[n][1]);
            }
        }
        #pragma unroll
        for (int n = 0; n < 4; ++n) {
            float2 h2 = *(const float2*)&hv[n0 + n][jc0];
            acc[n][0] += h2.x; acc[n][1] += h2.y;
        }
    }
    __syncthreads();
    #pragma unroll
    for (int n = 0; n < 4; ++n)
        *(float2*)&xs[n0 + n][jc0] = make_float2(acc[n][0], acc[n][1]);
    __syncthreads();
    // ---- LN reduce ----
    {
        int row = tid >> 4, part = tid & 15;
        float4 a = *(const float4*)&xs[row][part * 8];
        float4 b = *(const float4*)&xs[row][part * 8 + 4];
        float s1 = a.x + a.y + a.z + a.w + b.x + b.y + b.z + b.w;
        float s2 = a.x * a.x + a.y * a.y + a.z * a.z + a.w * a.w
                 + b.x * b.x + b.y * b.y + b.z * b.z + b.w * b.w;
        #pragma unroll
        for (int mq = 1; mq < 16; mq <<= 1) {
            s1 += __shfl_xor(s1, mq, 64);
            s2 += __shfl_xor(s2, mq, 64);
        }
        if (part == 0) { mv[row][0] = s1; mv[row][1] = s2; }
    }
    __syncthreads();
    // ---- LN apply ----
    {
        float ga = lng[jc0], gb = lng[jc1];
        float bba = lnb[jc0], bbb = lnb[jc1];
        #pragma unroll
        for (int n = 0; n < 4; ++n) {
            int row = n0 + n;
            float mu = mv[row][0] * (1.0f / 128.0f);
            float var = mv[row][1] * (1.0f / 128.0f) - mu * mu;
            float rs = rsqrtf(var + 1e-5f);
            float y0 = (xs[row][jc0] - mu) * rs * ga + bba;
            float y1 = (xs[row][jc1] - mu) * rs * gb + bbb;
            *(float2*)&hf[(size_t)(base + row) * 128 + jc0] = make_float2(y0, y1);
            *(u32*)&ybf[row * BPITCH + jc0] = pack2(y0, y1);
        }
    }
    if (Yw != nullptr) {
        __syncthreads();
        const int mat = w >> 1, half = w & 1;
        const int lrow = lane & 15, quad = lane >> 4;
        bf16x8 a[4];
        #pragma unroll
        for (int kc = 0; kc < 4; ++kc)
            a[kc] = *(const bf16x8*)(ybf + lrow * BPITCH + kc * 32 + quad * 8);
        u16* dst = mat ? Ydst : Ysrc;
        #pragma unroll
        for (int t = 0; t < 4; ++t) {
            int nt = half * 4 + t;
            f32x4 a4 = {0.f, 0.f, 0.f, 0.f};
            #pragma unroll
            for (int kc = 0; kc < 4; ++kc) {
                bf16x8 b = *(const bf16x8*)(Yw + (size_t)(((mat * 4 + kc) * 8 + nt) * 512 + lane * 8));
                a4 = __builtin_amdgcn_mfma_f32_16x16x32_bf16(a[kc], b, a4, 0, 0, 0);
            }
            #pragma unroll
            for (int r = 0; r < 4; ++r)
                dst[(size_t)(base + quad * 4 + r) * 128 + nt * 16 + lrow] = f2b(a4[r]);
        }
    }
}

// ---------------- output MLP (fp32 out, padded LDS) ----------------
__global__ __launch_bounds__(256) void k_out(const float* __restrict__ hf, const float* __restrict__ ow1p,
        const float* __restrict__ ob1, const float* __restrict__ ow2, const float* __restrict__ ob2,
        float* __restrict__ out) {
    const int tid = threadIdx.x;
    const int w = tid >> 6, lane = tid & 63;
    const int cg = lane & 15, ng = lane >> 4;
    const int jc0 = w * 32 + cg * 2, jc1 = jc0 + 1;
    const int n0 = ng * 4;
    const int base = blockIdx.x * 16;
    __shared__ alignas(16) float hv[16][PITCH];
    __shared__ float hid[16][PITCH];
    for (int q = tid; q < 512; q += 256) {
        int row = q >> 5, part = q & 31;
        *(float4*)&hv[row][part * 4] = ((const float4*)(hf + (size_t)base * 128))[q];
    }
    __syncthreads();
    float acc[4][2];
    {
        float ba = ob1[jc0], bb = ob1[jc1];
        #pragma unroll
        for (int n = 0; n < 4; ++n) { acc[n][0] = ba; acc[n][1] = bb; }
    }
    for (int kk = 0; kk < 32; ++kk) {
        float4 wa = *(const float4*)(ow1p + kk * 512 + jc0 * 4);
        float4 wb = *(const float4*)(ow1p + kk * 512 + jc1 * 4);
        #pragma unroll
        for (int n = 0; n < 4; ++n) {
            float4 s4 = *(const float4*)&hv[n0 + n][kk * 4];
            fma4(wa, s4, acc[n][0]);
            fma4(wb, s4, acc[n][1]);
        }
    }
    #pragma unroll
    for (int n = 0; n < 4; ++n) {
        hid[n0 + n][jc0] = silu(acc[n][0]);
        hid[n0 + n][jc1] = silu(acc[n][1]);
    }
    __syncthreads();
    if (tid < 48) {
        int n = tid / 3, cc = tid - n * 3;
        float o = ob2[cc];
        for (int k = 0; k < 128; ++k) o += hid[n][k] * ow2[k * 3 + cc];
        out[(size_t)(base + n) * 3 + cc] = o;
    }
}

extern "C" void kernel_launch(void* const* d_in, const int* in_sizes, int n_in,
                              void* d_out, int out_size, void* d_ws, size_t ws_size,
                              hipStream_t stream) {
    const float* x    = (const float*)d_in[0];
    const int* ei     = (const int*)d_in[1];
    const int* tptr   = (const int*)d_in[2];
    const float* tw1  = (const float*)d_in[3];
    const float* tb1  = (const float*)d_in[4];
    const float* tw2  = (const float*)d_in[5];
    const float* tb2  = (const float*)d_in[6];
    const float* nw1  = (const float*)d_in[7];
    const float* nb1  = (const float*)d_in[8];
    const float* nw2  = (const float*)d_in[9];
    const float* nb2  = (const float*)d_in[10];
    const float* pmw1 = (const float*)d_in[11];
    const float* pmb1 = (const float*)d_in[12];
    const float* pmw2 = (const float*)d_in[13];
    const float* pmb2 = (const float*)d_in[14];
    const float* phw1 = (const float*)d_in[15];
    const float* phb1 = (const float*)d_in[16];
    const float* phw2 = (const float*)d_in[17];
    const float* phb2 = (const float*)d_in[18];
    const float* lng  = (const float*)d_in[19];
    const float* lnb  = (const float*)d_in[20];
    const float* ow1  = (const float*)d_in[21];
    const float* ob1  = (const float*)d_in[22];
    const float* ow2  = (const float*)d_in[23];
    const float* ob2  = (const float*)d_in[24];
    float* out = (float*)d_out;

    char* wsp = (char*)d_ws;
    size_t off = 0;
    auto alloc = [&](size_t bytes) -> void* {
        void* p = wsp + off;
        off += (bytes + 255) & ~(size_t)255;
        return p;
    };
    int* hist    = (int*)alloc((size_t)NNODES * 4);
    int* cursor  = (int*)alloc((size_t)NNODES * 4);
    int* row_ptr = (int*)alloc((size_t)(NNODES + 1) * 4);
    int* ssrc    = (int*)alloc((size_t)NEDGES * 4);
    int* sdst    = (int*)alloc((size_t)NEDGES * 4);
    u16* Wr      = (u16*)alloc((size_t)3 * 8 * 64 * 8 * 2);
    u16* Yw      = (u16*)alloc((size_t)3 * 2 * 4 * 8 * 64 * 8 * 2);
    float* base1 = (float*)alloc(128 * 4);
    float* V1p   = (float*)alloc((size_t)3 * 256 * 128 * 4);
    float* V2p   = (float*)alloc((size_t)3 * 128 * 128 * 4);
    float* nw2p  = (float*)alloc((size_t)128 * 128 * 4);
    float* ow1p  = (float*)alloc((size_t)128 * 128 * 4);
    float* W2p   = (float*)alloc((size_t)3 * 128 * 128 * 4);
    float* Mp    = (float*)alloc((size_t)3 * 128 * 128 * 4);
    float* bvv   = (float*)alloc((size_t)3 * 128 * 4);
    float* hf    = (float*)alloc((size_t)NNODES * 128 * 4);
    u16* Ysrc    = (u16*)alloc((size_t)NNODES * 128 * 2);
    u16* Ydst    = (u16*)alloc((size_t)NNODES * 128 * 2);
    float* s_glob= (float*)alloc((size_t)NNODES * 128 * 4);

    (void)hipMemsetAsync(hist, 0, (size_t)NNODES * 4, stream);
    k_hist<<<NEDGES / 256, 256, 0, stream>>>(ei, hist);
    k_scan<<<1, 1024, 0, stream>>>(hist, row_ptr, cursor);
    k_scatter<<<NEDGES / 256, 256, 0, stream>>>(ei, cursor, ssrc, sdst);
    k_prep_wr<<<6, 256, 0, stream>>>(pmw1, pmb1, Wr);
    k_prep_yw<<<48, 256, 0, stream>>>(pmw1, Yw);

    PackM pm;
    for (int l = 0; l < 3; ++l) {
        pm.s[l] = pmw2 + (size_t)l * 16384;      pm.d[l] = W2p + (size_t)l * 16384;  pm.K[l] = 128;
        pm.s[3 + l] = phw2 + (size_t)l * 16384;  pm.d[3 + l] = V2p + (size_t)l * 16384; pm.K[3 + l] = 128;
        pm.s[6 + l] = phw1 + (size_t)l * 32768;  pm.d[6 + l] = V1p + (size_t)l * 32768; pm.K[6 + l] = 256;
    }
    pm.s[9] = nw2;  pm.d[9] = nw2p;  pm.K[9] = 128;
    pm.s[10] = ow1; pm.d[10] = ow1p; pm.K[10] = 128;
    k_pack<<<dim3(128, 11), 256, 0, stream>>>(pm);
    k_prep_m<<<dim3(9, 3), 256, 0, stream>>>(pmw2, pmb2, V1p, Mp, bvv);

    k_time<<<1, 128, 0, stream>>>(tptr, tw1, tb1, tw2, tb2, nw1, nb1, base1);
    k_h0<<<1250, 256, 0, stream>>>(x, base1, nw1, nw2p, nb2, Yw, hf, Ysrc, Ydst);

    // s_glob zeroed once here; k_node re-zeroes it for the next layer after reading
    (void)hipMemsetAsync(s_glob, 0, (size_t)NNODES * 128 * 4, stream);
    for (int l = 0; l < 3; ++l) {
        k_edge<<<NEDGES / 64, 512, 0, stream>>>(Ysrc, Ydst, x, ssrc, sdst,
                Wr + (size_t)l * 4096, s_glob);
        const u16* YwN = (l < 2) ? (Yw + (size_t)(l + 1) * 32768) : nullptr;
        k_node<<<1250, 256, 0, stream>>>(s_glob, row_ptr, hf,
                Mp + (size_t)l * 16384, V1p + (size_t)l * 32768, V2p + (size_t)l * 16384,
                bvv + l * 128, phb1 + l * 128, phb2 + l * 128, lng + l * 128, lnb + l * 128,
                YwN, Ysrc, Ydst);
    }
    k_out<<<1250, 256, 0, stream>>>(hf, ow1p, ob1, ow2, ob2, out);
}

// Round 16
// 543.620 us; speedup vs baseline: 1.9591x; 1.0594x over previous
//
#include <hip/hip_runtime.h>

typedef unsigned short u16;
typedef unsigned int u32;

#define NNODES 20000
#define NEDGES 640000
// GAMMA = 1/(2*(sqrt(2)/15)^2) = 56.25 exactly
#define RBF_GAMMA 56.25f
#define SQRT2 1.4142135623730951f
#define PITCH 132    // fp32 LDS row pitch
#define BPITCH 136   // bf16 LDS row pitch (u16)

typedef __bf16 bf16x8 __attribute__((ext_vector_type(8)));
typedef __bf16 bf16x2 __attribute__((ext_vector_type(2)));
typedef float f32x4 __attribute__((ext_vector_type(4)));

__device__ __forceinline__ float b2f(u16 u) {
    union { float f; u32 i; } x; x.i = ((u32)u) << 16; return x.f;
}
__device__ __forceinline__ float hi2f(u32 w) {
    union { float f; u32 i; } x; x.i = w & 0xffff0000u; return x.f;
}
__device__ __forceinline__ float lo2f(u32 w) {
    union { float f; u32 i; } x; x.i = w << 16; return x.f;
}
__device__ __forceinline__ u16 f2b(float f) {
    union { float f; u32 i; } x; x.f = f;
    u32 r = (x.i + 0x7fffu + ((x.i >> 16) & 1u)) >> 16;
    return (u16)r;
}
// pack 2 fp32 -> 2 bf16 (RNE)
__device__ __forceinline__ u32 pack2(float a, float b) {
#if __has_builtin(__builtin_amdgcn_cvt_pk_bf16_f32)
    union { bf16x2 v; u32 u; } x;
    x.v = __builtin_amdgcn_cvt_pk_bf16_f32(a, b);
    return x.u;
#else
    return (u32)f2b(a) | ((u32)f2b(b) << 16);
#endif
}
__device__ __forceinline__ float silu(float v) {
    return v * __builtin_amdgcn_rcpf(1.0f + __expf(-v));
}
__device__ __forceinline__ void fma4(float4 w, float4 s, float& acc) {
    acc = fmaf(w.x, s.x, acc);
    acc = fmaf(w.y, s.y, acc);
    acc = fmaf(w.z, s.z, acc);
    acc = fmaf(w.w, s.w, acc);
}

// ---------------- sort by dst (counting sort) ----------------
__global__ __launch_bounds__(256) void k_hist(const int* __restrict__ ei, int* __restrict__ hist) {
    int e = blockIdx.x * 256 + threadIdx.x;
    atomicAdd(&hist[ei[NEDGES + e]], 1);
}

__global__ __launch_bounds__(1024) void k_scan(const int* __restrict__ hist,
                                               int* __restrict__ row_ptr,
                                               int* __restrict__ cursor) {
    __shared__ int psum[1024];
    int t = threadIdx.x;
    int base = t * 20;
    int s = 0;
    if (base < NNODES)
        for (int i = 0; i < 20; ++i) s += hist[base + i];
    psum[t] = s;
    __syncthreads();
    for (int off = 1; off < 1024; off <<= 1) {
        int v = (t >= off) ? psum[t - off] : 0;
        __syncthreads();
        psum[t] += v;
        __syncthreads();
    }
    int excl = psum[t] - s;
    if (base < NNODES) {
        int run = excl;
        for (int i = 0; i < 20; ++i) {
            row_ptr[base + i] = run;
            cursor[base + i] = run;
            run += hist[base + i];
        }
    }
    if (t == 1023) row_ptr[NNODES] = psum[1023];
}

__global__ __launch_bounds__(256) void k_scatter(const int* __restrict__ ei, int* __restrict__ cursor,
                                                 int* __restrict__ ssrc, int* __restrict__ sdst) {
    int e = blockIdx.x * 256 + threadIdx.x;
    int d = ei[NEDGES + e];
    int pos = atomicAdd(&cursor[d], 1);
    ssrc[pos] = ei[e];
    sdst[pos] = d;
}

// ---------------- rbf-part W1 (rows 256..271) + b1 -> bf16 B-frag layout ----------------
__global__ __launch_bounds__(256) void k_prep_wr(const float* __restrict__ pmw1,
                                                 const float* __restrict__ pmb1,
                                                 u16* __restrict__ Wr) {
    int id = blockIdx.x * 256 + threadIdx.x;   // 1536 total
    if (id >= 1536) return;
    int l = id / 512; int r = id - l * 512;
    int nt = r >> 6, lane = r & 63;
    int col = nt * 16 + (lane & 15);
    alignas(16) u16 tmp[8];
    #pragma unroll
    for (int jj = 0; jj < 8; ++jj) {
        int kk = (lane >> 4) * 8 + jj;
        float v = 0.f;
        if (kk < 16) v = pmw1[l * 34816 + (256 + kk) * 128 + col];
        else if (kk == 16) v = pmb1[l * 128 + col];
        tmp[jj] = f2b(v);
    }
    *(uint4*)(Wr + (size_t)id * 8) = *(const uint4*)tmp;
}

// ---------------- generic fp32 [128][128] -> bf16 B-frag layout ----------------
// per-matrix layout: [kc(4)][nt(8)][lane(64)][8]  (16384 u16 each)
struct BfM { const float* s[10]; };
__global__ __launch_bounds__(256) void k_prep_bf(BfM bf, u16* __restrict__ dst) {
    int id = blockIdx.x * 256 + threadIdx.x;   // 20480 total
    if (id >= 20480) return;
    int mat = id >> 11;
    int r = id & 2047;
    int kc = r >> 9;
    int r2 = r & 511;
    int nt = r2 >> 6, lane = r2 & 63;
    int col = nt * 16 + (lane & 15);
    int kb = kc * 32 + (lane >> 4) * 8;
    const float* src = bf.s[mat];
    alignas(16) u16 tmp[8];
    #pragma unroll
    for (int jj = 0; jj < 8; ++jj)
        tmp[jj] = f2b(src[(kb + jj) * 128 + col]);
    *(uint4*)(dst + (size_t)id * 8) = *(const uint4*)tmp;
}

// ---------------- pack fp32 [K][128] -> [K/4][128][4] ----------------
struct PackM { const float* s[4]; float* d[4]; int K[4]; };
__global__ __launch_bounds__(256) void k_pack(PackM pm) {
    int m = blockIdx.y;
    int idx = blockIdx.x * 256 + threadIdx.x;
    if (idx >= pm.K[m] * 128) return;
    int k = idx >> 7, j = idx & 127;
    pm.d[m][(k >> 2) * 512 + j * 4 + (k & 3)] = pm.s[m][idx];
}

// ---------------- prep: M = W2 @ V1b (per layer, packed) and bv = b2 @ V1b ----------------
__global__ __launch_bounds__(256) void k_prep_m(const float* __restrict__ pmw2,
        const float* __restrict__ pmb2, const float* __restrict__ V1p,
        float* __restrict__ Mp, float* __restrict__ bvv) {
    const int l = blockIdx.y, bx = blockIdx.x;
    const float* V1 = V1p + (size_t)l * 32768;
    const int tid = threadIdx.x;
    const int w = tid >> 6, lane = tid & 63;
    const int cg = lane & 15, ng = lane >> 4;
    const int jc0 = w * 32 + cg * 2, jc1 = jc0 + 1;
    __shared__ alignas(16) float W2L[16][PITCH];
    __shared__ float b2L[128];
    if (bx < 8) {
        const float4* src = (const float4*)(pmw2 + (size_t)l * 16384 + bx * 16 * 128);
        for (int q = tid; q < 512; q += 256) {
            int row = q >> 5, part = q & 31;
            *(float4*)&W2L[row][part * 4] = src[q];
        }
        __syncthreads();
        int r0 = ng * 4;
        float acc[4][2];
        #pragma unroll
        for (int n = 0; n < 4; ++n) { acc[n][0] = 0.f; acc[n][1] = 0.f; }
        for (int mm = 0; mm < 32; ++mm) {
            float4 wa = *(const float4*)(V1 + (32 + mm) * 512 + jc0 * 4);
            float4 wb = *(const float4*)(V1 + (32 + mm) * 512 + jc1 * 4);
            #pragma unroll
            for (int n = 0; n < 4; ++n) {
                float4 s4 = *(const float4*)&W2L[r0 + n][mm * 4];
                fma4(wa, s4, acc[n][0]);
                fma4(wb, s4, acc[n][1]);
            }
        }
        #pragma unroll
        for (int n = 0; n < 4; ++n) {
            int kg = bx * 16 + r0 + n;
            Mp[(size_t)l * 16384 + (kg >> 2) * 512 + jc0 * 4 + (kg & 3)] = acc[n][0];
            Mp[(size_t)l * 16384 + (kg >> 2) * 512 + jc1 * 4 + (kg & 3)] = acc[n][1];
        }
    } else {
        if (tid < 128) b2L[tid] = pmb2[l * 128 + tid];
        __syncthreads();
        if (ng == 0) {
            float a0 = 0.f, a1 = 0.f;
            for (int mm = 0; mm < 32; ++mm) {
                float4 wa = *(const float4*)(V1 + (32 + mm) * 512 + jc0 * 4);
                float4 wb = *(const float4*)(V1 + (32 + mm) * 512 + jc1 * 4);
                float4 s4 = *(const float4*)&b2L[mm * 4];
                fma4(wa, s4, a0);
                fma4(wb, s4, a1);
            }
            bvv[l * 128 + jc0] = a0;
            bvv[l * 128 + jc1] = a1;
        }
    }
}

// ---------------- time embedding -> te -> base1 ----------------
__global__ __launch_bounds__(128) void k_time(const int* __restrict__ tptr,
        const float* __restrict__ tw1, const float* __restrict__ tb1,
        const float* __restrict__ tw2, const float* __restrict__ tb2,
        const float* __restrict__ nw1, const float* __restrict__ nb1,
        float* __restrict__ base1) {
    __shared__ float emb[128], hid[128], te[128];
    int j = threadIdx.x;
    int raw = tptr[0];
    float tv;
    if (raw >= 0 && raw < (1 << 24)) tv = (float)raw;
    else tv = __int_as_float(raw);
    float fr = expf(-9.210340371976184f * (float)(j & 63) / 63.0f);
    float a = tv * fr;
    emb[j] = (j < 64) ? sinf(a) : cosf(a);
    __syncthreads();
    float acc = tb1[j];
    for (int k = 0; k < 128; ++k) acc += emb[k] * tw1[k * 128 + j];
    hid[j] = silu(acc);
    __syncthreads();
    acc = tb2[j];
    for (int k = 0; k < 128; ++k) acc += hid[k] * tw2[k * 128 + j];
    te[j] = acc;
    __syncthreads();
    acc = nb1[j];
    for (int k = 0; k < 128; ++k) acc += te[k] * nw1[(3 + k) * 128 + j];
    base1[j] = acc;
}

// ---------------- input node MLP + MFMA Ysrc/Ydst ----------------
__global__ __launch_bounds__(256) void k_h0(const float* __restrict__ x, const float* __restrict__ base1,
        const float* __restrict__ nw1, const float* __restrict__ nw2p, const float* __restrict__ nb2,
        const u16* __restrict__ Yw,
        float* __restrict__ hf, u16* __restrict__ Ysrc, u16* __restrict__ Ydst) {
    const int tid = threadIdx.x;
    const int w = tid >> 6, lane = tid & 63;
    const int cg = lane & 15, ng = lane >> 4;
    const int jc0 = w * 32 + cg * 2, jc1 = jc0 + 1;
    const int n0 = ng * 4;
    const int base = blockIdx.x * 16;
    __shared__ alignas(16) float xl[16][4];
    __shared__ alignas(16) float hid[16][PITCH];
    __shared__ alignas(16) u16 hb16[16 * BPITCH];
    if (tid < 48) { int n = tid / 3, cc = tid - n * 3; xl[n][cc] = x[(size_t)(base + n) * 3 + cc]; }
    __syncthreads();
    {
        float w0a = nw1[jc0], w0b = nw1[jc1];
        float w1a = nw1[128 + jc0], w1b = nw1[128 + jc1];
        float w2a = nw1[256 + jc0], w2b = nw1[256 + jc1];
        float ba = base1[jc0], bb = base1[jc1];
        #pragma unroll
        for (int n = 0; n < 4; ++n) {
            int row = n0 + n;
            float x0 = xl[row][0], x1 = xl[row][1], x2 = xl[row][2];
            float2 v;
            v.x = silu(ba + x0 * w0a + x1 * w1a + x2 * w2a);
            v.y = silu(bb + x0 * w0b + x1 * w1b + x2 * w2b);
            *(float2*)&hid[row][jc0] = v;
        }
    }
    __syncthreads();
    float acc[4][2];
    {
        float ba = nb2[jc0], bb = nb2[jc1];
        #pragma unroll
        for (int n = 0; n < 4; ++n) { acc[n][0] = ba; acc[n][1] = bb; }
        for (int kk = 0; kk < 32; ++kk) {
            float4 wa = *(const float4*)(nw2p + kk * 512 + jc0 * 4);
            float4 wb = *(const float4*)(nw2p + kk * 512 + jc1 * 4);
            #pragma unroll
            for (int n = 0; n < 4; ++n) {
                float4 s4 = *(const float4*)&hid[n0 + n][kk * 4];
                fma4(wa, s4, acc[n][0]);
                fma4(wb, s4, acc[n][1]);
            }
        }
    }
    __syncthreads();   // all reads of hid done
    #pragma unroll
    for (int n = 0; n < 4; ++n) {
        int row = n0 + n;
        *(float2*)&hf[(size_t)(base + row) * 128 + jc0] = make_float2(acc[n][0], acc[n][1]);
        *(u32*)&hb16[row * BPITCH + jc0] = pack2(acc[n][0], acc[n][1]);
    }
    __syncthreads();
    // MFMA Y-GEMMs: wave w -> mat = w>>1, nt-half = w&1
    {
        const int mat = w >> 1, half = w & 1;
        const int lrow = lane & 15, quad = lane >> 4;
        bf16x8 a[4];
        #pragma unroll
        for (int kc = 0; kc < 4; ++kc)
            a[kc] = *(const bf16x8*)(hb16 + lrow * BPITCH + kc * 32 + quad * 8);
        u16* dst = mat ? Ydst : Ysrc;
        #pragma unroll
        for (int t = 0; t < 4; ++t) {
            int nt = half * 4 + t;
            f32x4 a4 = {0.f, 0.f, 0.f, 0.f};
            #pragma unroll
            for (int kc = 0; kc < 4; ++kc) {
                bf16x8 b = *(const bf16x8*)(Yw + (size_t)(((mat * 4 + kc) * 8 + nt) * 512 + lane * 8));
                a4 = __builtin_amdgcn_mfma_f32_16x16x32_bf16(a[kc], b, a4, 0, 0, 0);
            }
            #pragma unroll
            for (int r = 0; r < 4; ++r)
                dst[(size_t)(base + quad * 4 + r) * 128 + nt * 16 + lrow] = f2b(a4[r]);
        }
    }
}

// ---------------- edge kernel (proven): 512 threads, bf16 sst, 2x8-row epilogue ----------------
__global__ __launch_bounds__(512, 8) void k_edge(
        const u16* __restrict__ Ysrc, const u16* __restrict__ Ydst,
        const float* __restrict__ x,
        const int* __restrict__ ssrc, const int* __restrict__ sdst,
        const u16* __restrict__ Wr,
        float* __restrict__ s_glob) {
    __shared__ alignas(16) u16 sst[128 * 72];   // [col][row] bf16, pitch 72
    __shared__ alignas(16) u16 ys[64 * 128];    // staged Ysrc rows
    __shared__ float rv[64];
    __shared__ int s_d[65];
    __shared__ int s_s[64];
    const int tid = threadIdx.x;
    const int e0 = blockIdx.x * 64;
    if (tid < 64) {
        int s = ssrc[e0 + tid], d = sdst[e0 + tid];
        s_s[tid] = s; s_d[tid] = d;
        float ddx = x[s * 3] - x[d * 3];
        float ddy = x[s * 3 + 1] - x[d * 3 + 1];
        rv[tid] = sqrtf(ddx * ddx + ddy * ddy + 1e-8f);
    } else if (tid == 64) {
        s_d[64] = -1;
    }
    __syncthreads();
    #pragma unroll
    for (int i = 0; i < 2; ++i) {
        int cch = tid + i * 512;
        int e = cch >> 4, part = cch & 15;
        *(uint4*)(ys + e * 128 + part * 8) = *(const uint4*)(Ysrc + (size_t)s_s[e] * 128 + part * 8);
    }
    const int w = tid >> 6, lane = tid & 63;
    const int m = w & 3, nh = w >> 2;
    const int lrow = lane & 15, quad = lane >> 4;
    float r = rv[m * 16 + lrow];
    union { bf16x8 v; u16 u[8]; } af;
    #pragma unroll
    for (int j = 0; j < 8; ++j) {
        int kk = quad * 8 + j;
        float v;
        if (kk < 16) {
            float dd = r - SQRT2 * (float)kk / 15.0f;
            v = __expf(-RBF_GAMMA * dd * dd);
        } else v = (kk == 16) ? 1.0f : 0.0f;
        af.u[j] = f2b(v);
    }
    {
        const u16* Bp = Wr + lane * 8;
        #pragma unroll
        for (int t = 0; t < 4; ++t) {
            int nt = nh * 4 + t;
            f32x4 a4 = {0.f, 0.f, 0.f, 0.f};
            bf16x8 b = *(const bf16x8*)(Bp + nt * 512);
            a4 = __builtin_amdgcn_mfma_f32_16x16x32_bf16(af.v, b, a4, 0, 0, 0);
            int col = nt * 16 + lrow;
            u32 lo = pack2(a4[0], a4[1]);
            u32 hi = pack2(a4[2], a4[3]);
            *(uint2*)(sst + col * 72 + m * 16 + quad * 4) = make_uint2(lo, hi);
        }
    }
    __syncthreads();
    {
        const int col = tid & 127, q = tid >> 7;
        const int r0 = q * 16;
        float a = 0.f;
        int cd = s_d[r0];
        float yd = b2f(Ydst[(size_t)cd * 128 + col]);
        #pragma unroll
        for (int h = 0; h < 2; ++h) {
            uint4 c0 = *(const uint4*)(sst + col * 72 + r0 + h * 8);
            float sv8[8];
            sv8[0] = lo2f(c0.x); sv8[1] = hi2f(c0.x);
            sv8[2] = lo2f(c0.y); sv8[3] = hi2f(c0.y);
            sv8[4] = lo2f(c0.z); sv8[5] = hi2f(c0.z);
            sv8[6] = lo2f(c0.w); sv8[7] = hi2f(c0.w);
            #pragma unroll
            for (int i = 0; i < 8; ++i) {
                int rr = r0 + h * 8 + i;
                int nd = s_d[rr + 1];
                float v = sv8[i] + b2f(ys[rr * 128 + col]) + yd;
                a += silu(v);
                bool last = (h == 1 && i == 7);
                if (last || nd != cd) {
                    atomicAdd(&s_glob[(size_t)cd * 128 + col], a);
                    a = 0.f;
                    if (!last && nd != cd)
                        yd = b2f(Ydst[(size_t)nd * 128 + col]);
                }
                cd = nd;
            }
        }
    }
}

// ---------------- node update: M-folded, GEMM3 via MFMA, MFMA Ysrc/Ydst ----------------
__global__ __launch_bounds__(256) void k_node(float* __restrict__ s_glob, const int* __restrict__ row_ptr,
        float* __restrict__ hf,
        const float* __restrict__ Mp, const float* __restrict__ V1p, const u16* __restrict__ V2bf,
        const float* __restrict__ bv, const float* __restrict__ c1, const float* __restrict__ c2,
        const float* __restrict__ lng, const float* __restrict__ lnb,
        const u16* __restrict__ Yw,
        u16* __restrict__ Ysrc, u16* __restrict__ Ydst) {
    const int tid = threadIdx.x;
    const int w = tid >> 6, lane = tid & 63;
    const int cg = lane & 15, ng = lane >> 4;
    const int jc0 = w * 32 + cg * 2, jc1 = jc0 + 1;
    const int n0 = ng * 4;
    const int base = blockIdx.x * 16;
    const int lrow = lane & 15, quad = lane >> 4;
    __shared__ alignas(16) float sv[16][PITCH], hv[16][PITCH];
    __shared__ alignas(16) u16 ybf[16 * BPITCH];
    __shared__ float mv[16][2];
    __shared__ int rp[17];
    float (*xs)[PITCH] = sv;   // xs overwrites sv (dead after GEMM2')

    if (tid < 17) rp[tid] = row_ptr[base + tid];
    {
        const float4* sg4 = (const float4*)(s_glob + (size_t)base * 128);
        float4* sg4w = (float4*)(s_glob + (size_t)base * 128);
        const float4* hg4 = (const float4*)(hf + (size_t)base * 128);
        for (int q = tid; q < 512; q += 256) {
            int row = q >> 5, part = q & 31;
            *(float4*)&sv[row][part * 4] = sg4[q];
            *(float4*)&hv[row][part * 4] = hg4[q];
            sg4w[q] = make_float4(0.f, 0.f, 0.f, 0.f);
        }
    }
    __syncthreads();

    float acc[4][2];
    // ---- GEMM2': u_pre = hv@V1a + sv@M + deg*bv + c1 ; uv = silu(u_pre) -> bf16 tile ----
    {
        float ba = c1[jc0], bb = c1[jc1];
        float bva = bv[jc0], bvb = bv[jc1];
        #pragma unroll
        for (int n = 0; n < 4; ++n) {
            float dg = (float)(rp[n0 + n + 1] - rp[n0 + n]);
            acc[n][0] = ba + dg * bva; acc[n][1] = bb + dg * bvb;
        }
        for (int kk = 0; kk < 32; ++kk) {
            float4 wa = *(const float4*)(V1p + kk * 512 + jc0 * 4);
            float4 wb = *(const float4*)(V1p + kk * 512 + jc1 * 4);
            #pragma unroll
            for (int n = 0; n < 4; ++n) {
                float4 s4 = *(const float4*)&hv[n0 + n][kk * 4];
                fma4(wa, s4, acc[n][0]);
                fma4(wb, s4, acc[n][1]);
            }
        }
        for (int kk = 0; kk < 32; ++kk) {
            float4 wa = *(const float4*)(Mp + kk * 512 + jc0 * 4);
            float4 wb = *(const float4*)(Mp + kk * 512 + jc1 * 4);
            #pragma unroll
            for (int n = 0; n < 4; ++n) {
                float4 s4 = *(const float4*)&sv[n0 + n][kk * 4];
                fma4(wa, s4, acc[n][0]);
                fma4(wb, s4, acc[n][1]);
            }
        }
        #pragma unroll
        for (int n = 0; n < 4; ++n)
            *(u32*)&ybf[(n0 + n) * BPITCH + jc0] = pack2(silu(acc[n][0]), silu(acc[n][1]));
    }
    __syncthreads();   // sv reads done; uv(bf16) ready
    // ---- GEMM3 (MFMA): o = uv @ V2 + c2 ; xj = hv + o -> xs (C-layout) ----
    {
        bf16x8 a[4];
        #pragma unroll
        for (int kc = 0; kc < 4; ++kc)
            a[kc] = *(const bf16x8*)(ybf + lrow * BPITCH + kc * 32 + quad * 8);
        #pragma unroll
        for (int t = 0; t < 2; ++t) {
            int nt = w * 2 + t;
            f32x4 a4 = {0.f, 0.f, 0.f, 0.f};
            #pragma unroll
            for (int kc = 0; kc < 4; ++kc) {
                bf16x8 b = *(const bf16x8*)(V2bf + (size_t)((kc * 8 + nt) * 512 + lane * 8));
                a4 = __builtin_amdgcn_mfma_f32_16x16x32_bf16(a[kc], b, a4, 0, 0, 0);
            }
            int colC = nt * 16 + lrow;
            float c2v = c2[colC];
            #pragma unroll
            for (int r = 0; r < 4; ++r) {
                int R = quad * 4 + r;
                xs[R][colC] = a4[r] + c2v + hv[R][colC];
            }
        }
    }
    __syncthreads();
    // ---- LN reduce ----
    {
        int row = tid >> 4, part = tid & 15;
        float4 a = *(const float4*)&xs[row][part * 8];
        float4 b = *(const float4*)&xs[row][part * 8 + 4];
        float s1 = a.x + a.y + a.z + a.w + b.x + b.y + b.z + b.w;
        float s2 = a.x * a.x + a.y * a.y + a.z * a.z + a.w * a.w
                 + b.x * b.x + b.y * b.y + b.z * b.z + b.w * b.w;
        #pragma unroll
        for (int mq = 1; mq < 16; mq <<= 1) {
            s1 += __shfl_xor(s1, mq, 64);
            s2 += __shfl_xor(s2, mq, 64);
        }
        if (part == 0) { mv[row][0] = s1; mv[row][1] = s2; }
    }
    __syncthreads();
    // ---- LN apply (writes y to hf + bf16 tile, overwriting uv) ----
    {
        float ga = lng[jc0], gb = lng[jc1];
        float bba = lnb[jc0], bbb = lnb[jc1];
        #pragma unroll
        for (int n = 0; n < 4; ++n) {
            int row = n0 + n;
            float mu = mv[row][0] * (1.0f / 128.0f);
            float var = mv[row][1] * (1.0f / 128.0f) - mu * mu;
            float rs = rsqrtf(var + 1e-5f);
            float y0 = (xs[row][jc0] - mu) * rs * ga + bba;
            float y1 = (xs[row][jc1] - mu) * rs * gb + bbb;
            *(float2*)&hf[(size_t)(base + row) * 128 + jc0] = make_float2(y0, y1);
            *(u32*)&ybf[row * BPITCH + jc0] = pack2(y0, y1);
        }
    }
    if (Yw != nullptr) {
        __syncthreads();
        const int mat = w >> 1, half = w & 1;
        bf16x8 a[4];
        #pragma unroll
        for (int kc = 0; kc < 4; ++kc)
            a[kc] = *(const bf16x8*)(ybf + lrow * BPITCH + kc * 32 + quad * 8);
        u16* dst = mat ? Ydst : Ysrc;
        #pragma unroll
        for (int t = 0; t < 4; ++t) {
            int nt = half * 4 + t;
            f32x4 a4 = {0.f, 0.f, 0.f, 0.f};
            #pragma unroll
            for (int kc = 0; kc < 4; ++kc) {
                bf16x8 b = *(const bf16x8*)(Yw + (size_t)(((mat * 4 + kc) * 8 + nt) * 512 + lane * 8));
                a4 = __builtin_amdgcn_mfma_f32_16x16x32_bf16(a[kc], b, a4, 0, 0, 0);
            }
            #pragma unroll
            for (int r = 0; r < 4; ++r)
                dst[(size_t)(base + quad * 4 + r) * 128 + nt * 16 + lrow] = f2b(a4[r]);
        }
    }
}

// ---------------- output MLP: MFMA h@ow1, scalar 3-col tail ----------------
__global__ __launch_bounds__(256) void k_out(const float* __restrict__ hf, const u16* __restrict__ ow1bf,
        const float* __restrict__ ob1, const float* __restrict__ ow2, const float* __restrict__ ob2,
        float* __restrict__ out) {
    const int tid = threadIdx.x;
    const int w = tid >> 6, lane = tid & 63;
    const int lrow = lane & 15, quad = lane >> 4;
    const int base = blockIdx.x * 16;
    __shared__ alignas(16) u16 hb16[16 * BPITCH];
    __shared__ float hid[16][PITCH];
    for (int q = tid; q < 512; q += 256) {
        int row = q >> 5, part = q & 31;
        float4 v = ((const float4*)(hf + (size_t)base * 128))[q];
        *(uint2*)&hb16[row * BPITCH + part * 4] = make_uint2(pack2(v.x, v.y), pack2(v.z, v.w));
    }
    __syncthreads();
    {
        bf16x8 a[4];
        #pragma unroll
        for (int kc = 0; kc < 4; ++kc)
            a[kc] = *(const bf16x8*)(hb16 + lrow * BPITCH + kc * 32 + quad * 8);
        #pragma unroll
        for (int t = 0; t < 2; ++t) {
            int nt = w * 2 + t;
            f32x4 a4 = {0.f, 0.f, 0.f, 0.f};
            #pragma unroll
            for (int kc = 0; kc < 4; ++kc) {
                bf16x8 b = *(const bf16x8*)(ow1bf + (size_t)((kc * 8 + nt) * 512 + lane * 8));
                a4 = __builtin_amdgcn_mfma_f32_16x16x32_bf16(a[kc], b, a4, 0, 0, 0);
            }
            int colC = nt * 16 + lrow;
            float b1v = ob1[colC];
            #pragma unroll
            for (int r = 0; r < 4; ++r)
                hid[quad * 4 + r][colC] = silu(a4[r] + b1v);
        }
    }
    __syncthreads();
    if (tid < 48) {
        int n = tid / 3, cc = tid - n * 3;
        float o = ob2[cc];
        for (int k = 0; k < 128; ++k) o += hid[n][k] * ow2[k * 3 + cc];
        out[(size_t)(base + n) * 3 + cc] = o;
    }
}

extern "C" void kernel_launch(void* const* d_in, const int* in_sizes, int n_in,
                              void* d_out, int out_size, void* d_ws, size_t ws_size,
                              hipStream_t stream) {
    const float* x    = (const float*)d_in[0];
    const int* ei     = (const int*)d_in[1];
    const int* tptr   = (const int*)d_in[2];
    const float* tw1  = (const float*)d_in[3];
    const float* tb1  = (const float*)d_in[4];
    const float* tw2  = (const float*)d_in[5];
    const float* tb2  = (const float*)d_in[6];
    const float* nw1  = (const float*)d_in[7];
    const float* nb1  = (const float*)d_in[8];
    const float* nw2  = (const float*)d_in[9];
    const float* nb2  = (const float*)d_in[10];
    const float* pmw1 = (const float*)d_in[11];
    const float* pmb1 = (const float*)d_in[12];
    const float* pmw2 = (const float*)d_in[13];
    const float* pmb2 = (const float*)d_in[14];
    const float* phw1 = (const float*)d_in[15];
    const float* phb1 = (const float*)d_in[16];
    const float* phw2 = (const float*)d_in[17];
    const float* phb2 = (const float*)d_in[18];
    const float* lng  = (const float*)d_in[19];
    const float* lnb  = (const float*)d_in[20];
    const float* ow1  = (const float*)d_in[21];
    const float* ob1  = (const float*)d_in[22];
    const float* ow2  = (const float*)d_in[23];
    const float* ob2  = (const float*)d_in[24];
    float* out = (float*)d_out;

    char* wsp = (char*)d_ws;
    size_t off = 0;
    auto alloc = [&](size_t bytes) -> void* {
        void* p = wsp + off;
        off += (bytes + 255) & ~(size_t)255;
        return p;
    };
    int* hist    = (int*)alloc((size_t)NNODES * 4);
    int* cursor  = (int*)alloc((size_t)NNODES * 4);
    int* row_ptr = (int*)alloc((size_t)(NNODES + 1) * 4);
    int* ssrc    = (int*)alloc((size_t)NEDGES * 4);
    int* sdst    = (int*)alloc((size_t)NEDGES * 4);
    u16* Wr      = (u16*)alloc((size_t)3 * 8 * 64 * 8 * 2);
    u16* BF      = (u16*)alloc((size_t)10 * 16384 * 2);   // 6 Yw + 3 V2 + 1 ow1 (bf16 frag)
    float* base1 = (float*)alloc(128 * 4);
    float* V1p   = (float*)alloc((size_t)3 * 256 * 128 * 4);
    float* nw2p  = (float*)alloc((size_t)128 * 128 * 4);
    float* Mp    = (float*)alloc((size_t)3 * 128 * 128 * 4);
    float* bvv   = (float*)alloc((size_t)3 * 128 * 4);
    float* hf    = (float*)alloc((size_t)NNODES * 128 * 4);
    u16* Ysrc    = (u16*)alloc((size_t)NNODES * 128 * 2);
    u16* Ydst    = (u16*)alloc((size_t)NNODES * 128 * 2);
    float* s_glob= (float*)alloc((size_t)NNODES * 128 * 4);

    (void)hipMemsetAsync(hist, 0, (size_t)NNODES * 4, stream);
    k_hist<<<NEDGES / 256, 256, 0, stream>>>(ei, hist);
    k_scan<<<1, 1024, 0, stream>>>(hist, row_ptr, cursor);
    k_scatter<<<NEDGES / 256, 256, 0, stream>>>(ei, cursor, ssrc, sdst);
    k_prep_wr<<<6, 256, 0, stream>>>(pmw1, pmb1, Wr);

    BfM bf;
    for (int l = 0; l < 3; ++l) {
        bf.s[l * 2 + 0] = pmw1 + (size_t)l * 34816;           // Y-src weights (W1 rows 0..127)
        bf.s[l * 2 + 1] = pmw1 + (size_t)l * 34816 + 16384;   // Y-dst weights (W1 rows 128..255)
        bf.s[6 + l] = phw2 + (size_t)l * 16384;               // V2
    }
    bf.s[9] = ow1;
    k_prep_bf<<<80, 256, 0, stream>>>(bf, BF);

    PackM pm;
    for (int l = 0; l < 3; ++l) {
        pm.s[l] = phw1 + (size_t)l * 32768; pm.d[l] = V1p + (size_t)l * 32768; pm.K[l] = 256;
    }
    pm.s[3] = nw2; pm.d[3] = nw2p; pm.K[3] = 128;
    k_pack<<<dim3(128, 4), 256, 0, stream>>>(pm);
    k_prep_m<<<dim3(9, 3), 256, 0, stream>>>(pmw2, pmb2, V1p, Mp, bvv);

    k_time<<<1, 128, 0, stream>>>(tptr, tw1, tb1, tw2, tb2, nw1, nb1, base1);
    k_h0<<<1250, 256, 0, stream>>>(x, base1, nw1, nw2p, nb2, BF, hf, Ysrc, Ydst);

    (void)hipMemsetAsync(s_glob, 0, (size_t)NNODES * 128 * 4, stream);
    for (int l = 0; l < 3; ++l) {
        k_edge<<<NEDGES / 64, 512, 0, stream>>>(Ysrc, Ydst, x, ssrc, sdst,
                Wr + (size_t)l * 4096, s_glob);
        const u16* YwN = (l < 2) ? (BF + (size_t)(l + 1) * 32768) : nullptr;
        k_node<<<1250, 256, 0, stream>>>(s_glob, row_ptr, hf,
                Mp + (size_t)l * 16384, V1p + (size_t)l * 32768, BF + (size_t)(6 + l) * 16384,
                bvv + l * 128, phb1 + l * 128, phb2 + l * 128, lng + l * 128, lnb + l * 128,
                YwN, Ysrc, Ydst);
    }
    k_out<<<1250, 256, 0, stream>>>(hf, BF + (size_t)9 * 16384, ob1, ow2, ob2, out);
}